// Round 1
// baseline (717.455 us; speedup 1.0000x reference)
//
#include <hip/hip_runtime.h>
#include <math.h>

#define NN 100000
#define EE 1600000
#define HH 128
#define DX 64
#define CC 8
#define EPSV 1e-5f

#define CHUNK 512
#define NSCAN ((NN + CHUNK - 1) / CHUNK)   // 196

// ---------------- graph preprocessing ----------------

__global__ void k_zero(int* __restrict__ cnt, float* __restrict__ stats) {
    int i = blockIdx.x * blockDim.x + threadIdx.x;
    if (i < NN) cnt[i] = 0;
    if (i < 512) stats[i] = 0.f;
}

__global__ void k_count(const int* __restrict__ dst, int* __restrict__ cnt) {
    int e = blockIdx.x * blockDim.x + threadIdx.x;
    if (e < EE) atomicAdd(&cnt[dst[e]], 1);
}

// per-chunk partial sums of cnt; also computes dinv = rsqrt(1+deg)
__global__ void k_part(const int* __restrict__ cnt, int* __restrict__ part,
                       float* __restrict__ dinv) {
    __shared__ int ls[256];
    int b = blockIdx.x, t = threadIdx.x;
    int base = b * CHUNK;
    int s = 0;
    for (int i = t; i < CHUNK; i += 256) {
        int idx = base + i;
        if (idx < NN) {
            int c = cnt[idx];
            s += c;
            dinv[idx] = rsqrtf(1.0f + (float)c);
        }
    }
    ls[t] = s; __syncthreads();
    for (int d = 128; d > 0; d >>= 1) {
        if (t < d) ls[t] += ls[t + d];
        __syncthreads();
    }
    if (t == 0) part[b] = ls[0];
}

// exclusive scan of the NSCAN partials (single block)
__global__ void k_scanpart(int* __restrict__ part) {
    __shared__ int ls[256];
    int t = threadIdx.x;
    int v = (t < NSCAN) ? part[t] : 0;
    ls[t] = v; __syncthreads();
    for (int d = 1; d < 256; d <<= 1) {
        int x = (t >= d) ? ls[t - d] : 0;
        __syncthreads();
        ls[t] += x;
        __syncthreads();
    }
    if (t < NSCAN) part[t] = ls[t] - v;   // exclusive
}

// per-chunk exclusive scan -> row_ptr, cursor (blockDim = 512)
__global__ void k_scanchunk(const int* __restrict__ cnt, const int* __restrict__ part,
                            int* __restrict__ row_ptr, int* __restrict__ cursor) {
    __shared__ int ls[CHUNK];
    int b = blockIdx.x, t = threadIdx.x;
    int idx = b * CHUNK + t;
    int v = (idx < NN) ? cnt[idx] : 0;
    ls[t] = v; __syncthreads();
    for (int d = 1; d < CHUNK; d <<= 1) {
        int x = (t >= d) ? ls[t - d] : 0;
        __syncthreads();
        ls[t] += x;
        __syncthreads();
    }
    if (idx < NN) {
        int excl = part[b] + ls[t] - v;
        row_ptr[idx] = excl;
        cursor[idx] = excl;
    }
}

__global__ void k_scatter(const int* __restrict__ src, const int* __restrict__ dst,
                          int* __restrict__ cursor, int* __restrict__ col) {
    int e = blockIdx.x * blockDim.x + threadIdx.x;
    if (e < EE) {
        int d = dst[e];
        int pos = atomicAdd(&cursor[d], 1);
        col[pos] = src[e];
    }
}

// constant part of GEMM1: scene_context @ W1[64:128,:]
__global__ void k_cvec(const float* __restrict__ sctx, const float* __restrict__ W1,
                       float* __restrict__ cvec) {
    int f = threadIdx.x;  // 128 threads
    float s = 0.f;
    #pragma unroll
    for (int j = 0; j < 64; ++j) s += sctx[j] * W1[(64 + j) * HH + f];
    cvec[f] = s;
}

// ---------------- GEMM1: hlin = x @ W1[0:64,:] + cvec ----------------

__global__ __launch_bounds__(256) void k_gemm1(const float* __restrict__ x,
                                               const float* __restrict__ W1,
                                               const float* __restrict__ cvec,
                                               float* __restrict__ hlin) {
    __shared__ float hsT[32][64];
    __shared__ float Wt[32][128];
    int t = threadIdx.x;
    int n0 = blockIdx.x * 64;
    int tc = t & 15, tr = t >> 4;
    int f0 = tc * 8, r0 = tr * 4;
    float acc[4][8];
    #pragma unroll
    for (int i = 0; i < 4; ++i)
        #pragma unroll
        for (int j = 0; j < 8; ++j) acc[i][j] = 0.f;

    for (int kc = 0; kc < DX; kc += 32) {
        #pragma unroll
        for (int l = 0; l < 2; ++l) {
            int idx = t + l * 256;          // 512 float4 loads = 2048 elems
            int r = idx >> 3;
            int kq = idx & 7;
            int n = n0 + r;
            float4 v = make_float4(0.f, 0.f, 0.f, 0.f);
            if (n < NN) v = *(const float4*)&x[(size_t)n * DX + kc + kq * 4];
            hsT[kq * 4 + 0][r] = v.x;
            hsT[kq * 4 + 1][r] = v.y;
            hsT[kq * 4 + 2][r] = v.z;
            hsT[kq * 4 + 3][r] = v.w;
        }
        #pragma unroll
        for (int l = 0; l < 4; ++l) {
            int idx = t + l * 256;          // 1024 float4 = 4096 elems
            int k = idx >> 5;
            int f4 = idx & 31;
            *(float4*)&Wt[k][f4 * 4] = *(const float4*)&W1[(size_t)(kc + k) * HH + f4 * 4];
        }
        __syncthreads();
        #pragma unroll
        for (int k = 0; k < 32; ++k) {
            float4 hv = *(float4*)&hsT[k][r0];
            float4 w0 = *(float4*)&Wt[k][f0];
            float4 w1 = *(float4*)&Wt[k][f0 + 4];
            float h_[4] = {hv.x, hv.y, hv.z, hv.w};
            float w_[8] = {w0.x, w0.y, w0.z, w0.w, w1.x, w1.y, w1.z, w1.w};
            #pragma unroll
            for (int i = 0; i < 4; ++i)
                #pragma unroll
                for (int j = 0; j < 8; ++j) acc[i][j] = fmaf(h_[i], w_[j], acc[i][j]);
        }
        __syncthreads();
    }
    #pragma unroll
    for (int i = 0; i < 4; ++i) {
        int n = n0 + r0 + i;
        if (n < NN) {
            float4 o0, o1;
            o0.x = acc[i][0] + cvec[f0 + 0];
            o0.y = acc[i][1] + cvec[f0 + 1];
            o0.z = acc[i][2] + cvec[f0 + 2];
            o0.w = acc[i][3] + cvec[f0 + 3];
            o1.x = acc[i][4] + cvec[f0 + 4];
            o1.y = acc[i][5] + cvec[f0 + 5];
            o1.z = acc[i][6] + cvec[f0 + 6];
            o1.w = acc[i][7] + cvec[f0 + 7];
            *(float4*)&hlin[(size_t)n * HH + f0] = o0;
            *(float4*)&hlin[(size_t)n * HH + f0 + 4] = o1;
        }
    }
}

// ---------------- GEMM2: hlin = relu(bn1(hbuf)) @ W2 ----------------

__global__ __launch_bounds__(256) void k_gemm2(const float* __restrict__ hin,
                                               const float* __restrict__ W2,
                                               const float* __restrict__ stats,
                                               const float* __restrict__ g,
                                               const float* __restrict__ be,
                                               float* __restrict__ hlin) {
    __shared__ float hsT[32][64];
    __shared__ float Wt[32][128];
    __shared__ float asc[128], csc[128];
    int t = threadIdx.x;
    if (t < 128) {
        float mu  = stats[t] * (1.0f / NN);
        float var = stats[128 + t] * (1.0f / NN) - mu * mu;
        float rs  = rsqrtf(var + EPSV);
        float a   = g[t] * rs;
        asc[t] = a;
        csc[t] = be[t] - mu * a;
    }
    __syncthreads();

    int n0 = blockIdx.x * 64;
    int tc = t & 15, tr = t >> 4;
    int f0 = tc * 8, r0 = tr * 4;
    float acc[4][8];
    #pragma unroll
    for (int i = 0; i < 4; ++i)
        #pragma unroll
        for (int j = 0; j < 8; ++j) acc[i][j] = 0.f;

    for (int kc = 0; kc < HH; kc += 32) {
        #pragma unroll
        for (int l = 0; l < 2; ++l) {
            int idx = t + l * 256;
            int r = idx >> 3;
            int kq = idx & 7;
            int n = n0 + r;
            float4 v = make_float4(0.f, 0.f, 0.f, 0.f);
            if (n < NN) v = *(const float4*)&hin[(size_t)n * HH + kc + kq * 4];
            int kk = kc + kq * 4;
            hsT[kq * 4 + 0][r] = fmaxf(fmaf(v.x, asc[kk + 0], csc[kk + 0]), 0.f);
            hsT[kq * 4 + 1][r] = fmaxf(fmaf(v.y, asc[kk + 1], csc[kk + 1]), 0.f);
            hsT[kq * 4 + 2][r] = fmaxf(fmaf(v.z, asc[kk + 2], csc[kk + 2]), 0.f);
            hsT[kq * 4 + 3][r] = fmaxf(fmaf(v.w, asc[kk + 3], csc[kk + 3]), 0.f);
        }
        #pragma unroll
        for (int l = 0; l < 4; ++l) {
            int idx = t + l * 256;
            int k = idx >> 5;
            int f4 = idx & 31;
            *(float4*)&Wt[k][f4 * 4] = *(const float4*)&W2[(size_t)(kc + k) * HH + f4 * 4];
        }
        __syncthreads();
        #pragma unroll
        for (int k = 0; k < 32; ++k) {
            float4 hv = *(float4*)&hsT[k][r0];
            float4 w0 = *(float4*)&Wt[k][f0];
            float4 w1 = *(float4*)&Wt[k][f0 + 4];
            float h_[4] = {hv.x, hv.y, hv.z, hv.w};
            float w_[8] = {w0.x, w0.y, w0.z, w0.w, w1.x, w1.y, w1.z, w1.w};
            #pragma unroll
            for (int i = 0; i < 4; ++i)
                #pragma unroll
                for (int j = 0; j < 8; ++j) acc[i][j] = fmaf(h_[i], w_[j], acc[i][j]);
        }
        __syncthreads();
    }
    #pragma unroll
    for (int i = 0; i < 4; ++i) {
        int n = n0 + r0 + i;
        if (n < NN) {
            float4 o0 = make_float4(acc[i][0], acc[i][1], acc[i][2], acc[i][3]);
            float4 o1 = make_float4(acc[i][4], acc[i][5], acc[i][6], acc[i][7]);
            *(float4*)&hlin[(size_t)n * HH + f0] = o0;
            *(float4*)&hlin[(size_t)n * HH + f0 + 4] = o1;
        }
    }
}

// ---------------- SpMM: hout = relu(A @ hlin + self + b) ----------------
// one wave per node; lane handles 2 features

__global__ __launch_bounds__(256) void k_spmm(const float* __restrict__ hlin,
                                              const int* __restrict__ row_ptr,
                                              const int* __restrict__ cnt,
                                              const int* __restrict__ col,
                                              const float* __restrict__ dinv,
                                              const float* __restrict__ b,
                                              float* __restrict__ hout) {
    int wave = threadIdx.x >> 6;
    int lane = threadIdx.x & 63;
    int n = blockIdx.x * 4 + wave;
    if (n >= NN) return;
    int f0 = lane * 2;
    float dn = dinv[n];
    float2 hv = *(const float2*)&hlin[(size_t)n * HH + f0];
    float sc = dn * dn;
    float ax = hv.x * sc, ay = hv.y * sc;
    int start = row_ptr[n], len = cnt[n];
    for (int j = 0; j < len; ++j) {
        int s = col[start + j];
        float nr = dinv[s] * dn;
        float2 v = *(const float2*)&hlin[(size_t)s * HH + f0];
        ax = fmaf(v.x, nr, ax);
        ay = fmaf(v.y, nr, ay);
    }
    float2 bb = *(const float2*)&b[f0];
    ax = fmaxf(ax + bb.x, 0.f);
    ay = fmaxf(ay + bb.y, 0.f);
    *(float2*)&hout[(size_t)n * HH + f0] = make_float2(ax, ay);
}

// ---------------- BN stats: per-feature sum & sumsq ----------------

__global__ __launch_bounds__(256) void k_stats(const float* __restrict__ h,
                                               float* __restrict__ sums) {
    __shared__ float ls[256], ls2[256];
    int t = threadIdx.x;
    int f = t & 127, half = t >> 7;
    float s = 0.f, s2 = 0.f;
    for (int row = blockIdx.x * 2 + half; row < NN; row += gridDim.x * 2) {
        float v = h[(size_t)row * HH + f];
        s += v;
        s2 += v * v;
    }
    ls[t] = s; ls2[t] = s2; __syncthreads();
    if (t < 128) {
        atomicAdd(&sums[f], ls[t] + ls[t + 128]);
        atomicAdd(&sums[128 + f], ls2[t] + ls2[t + 128]);
    }
}

// ---------------- output head: out = relu(bn2(h)) @ Wout + bout ----------------

__global__ __launch_bounds__(256) void k_out(const float* __restrict__ h,
                                             const float* __restrict__ stats,
                                             const float* __restrict__ g,
                                             const float* __restrict__ be,
                                             const float* __restrict__ Wout,
                                             const float* __restrict__ bout,
                                             float* __restrict__ out) {
    __shared__ float hs[32][132];
    __shared__ float Wl[128][8];
    __shared__ float asc[128], csc[128];
    int t = threadIdx.x;
    if (t < 128) {
        float mu  = stats[256 + t] * (1.0f / NN);
        float var = stats[384 + t] * (1.0f / NN) - mu * mu;
        float rs  = rsqrtf(var + EPSV);
        float a   = g[t] * rs;
        asc[t] = a;
        csc[t] = be[t] - mu * a;
    }
    #pragma unroll
    for (int l = 0; l < 4; ++l) {
        int idx = t + l * 256;
        Wl[idx >> 3][idx & 7] = Wout[idx];
    }
    __syncthreads();

    int n0 = blockIdx.x * 32;
    #pragma unroll
    for (int l = 0; l < 4; ++l) {
        int idx4 = t + l * 256;        // 1024 float4 = 4096 elems
        int r = idx4 >> 5;
        int f4 = idx4 & 31;
        float4 v = *(const float4*)&h[(size_t)(n0 + r) * HH + f4 * 4];
        int kk = f4 * 4;
        hs[r][kk + 0] = fmaxf(fmaf(v.x, asc[kk + 0], csc[kk + 0]), 0.f);
        hs[r][kk + 1] = fmaxf(fmaf(v.y, asc[kk + 1], csc[kk + 1]), 0.f);
        hs[r][kk + 2] = fmaxf(fmaf(v.z, asc[kk + 2], csc[kk + 2]), 0.f);
        hs[r][kk + 3] = fmaxf(fmaf(v.w, asc[kk + 3], csc[kk + 3]), 0.f);
    }
    __syncthreads();

    int c = t & 7, rl = t >> 3;        // 32 rows x 8 cols
    float acc = 0.f;
    #pragma unroll 8
    for (int k = 0; k < 128; ++k) acc = fmaf(hs[rl][k], Wl[k][c], acc);
    out[(size_t)(n0 + rl) * CC + c] = acc + bout[c];
}

// ---------------- launch ----------------

extern "C" void kernel_launch(void* const* d_in, const int* in_sizes, int n_in,
                              void* d_out, int out_size, void* d_ws, size_t ws_size,
                              hipStream_t stream) {
    const float* x    = (const float*)d_in[0];
    const int*   src  = (const int*)d_in[1];
    const int*   dst  = (const int*)d_in[2];
    const float* sctx = (const float*)d_in[3];
    const float* W1   = (const float*)d_in[4];
    const float* b1   = (const float*)d_in[5];
    const float* g1   = (const float*)d_in[6];
    const float* be1  = (const float*)d_in[7];
    const float* W2   = (const float*)d_in[8];
    const float* b2   = (const float*)d_in[9];
    const float* g2   = (const float*)d_in[10];
    const float* be2  = (const float*)d_in[11];
    const float* Wout = (const float*)d_in[12];
    const float* bout = (const float*)d_in[13];
    float* out = (float*)d_out;

    char* p = (char*)d_ws;
    auto carve = [&](size_t bytes) -> char* {
        char* r = p;
        p += (bytes + 255) & ~(size_t)255;
        return r;
    };
    float* hlin   = (float*)carve((size_t)NN * HH * 4);
    float* hbuf   = (float*)carve((size_t)NN * HH * 4);
    int*   col    = (int*)carve((size_t)EE * 4);
    int*   cnt    = (int*)carve((size_t)NN * 4);
    int*   rowp   = (int*)carve((size_t)NN * 4);
    int*   cursor = (int*)carve((size_t)NN * 4);
    float* dinv   = (float*)carve((size_t)NN * 4);
    int*   part   = (int*)carve((size_t)NSCAN * 4);
    float* cvec   = (float*)carve(128 * 4);
    float* stats  = (float*)carve(512 * 4);

    k_zero<<<391, 256, 0, stream>>>(cnt, stats);
    k_count<<<(EE + 255) / 256, 256, 0, stream>>>(dst, cnt);
    k_part<<<NSCAN, 256, 0, stream>>>(cnt, part, dinv);
    k_scanpart<<<1, 256, 0, stream>>>(part);
    k_scanchunk<<<NSCAN, 512, 0, stream>>>(cnt, part, rowp, cursor);
    k_scatter<<<(EE + 255) / 256, 256, 0, stream>>>(src, dst, cursor, col);
    k_cvec<<<1, 128, 0, stream>>>(sctx, W1, cvec);

    k_gemm1<<<(NN + 63) / 64, 256, 0, stream>>>(x, W1, cvec, hlin);
    k_spmm<<<(NN + 3) / 4, 256, 0, stream>>>(hlin, rowp, cnt, col, dinv, b1, hbuf);
    k_stats<<<512, 256, 0, stream>>>(hbuf, stats);

    k_gemm2<<<(NN + 63) / 64, 256, 0, stream>>>(hbuf, W2, stats, g1, be1, hlin);
    k_spmm<<<(NN + 3) / 4, 256, 0, stream>>>(hlin, rowp, cnt, col, dinv, b2, hbuf);
    k_stats<<<512, 256, 0, stream>>>(hbuf, stats + 256);

    k_out<<<NN / 32, 256, 0, stream>>>(hbuf, stats, g2, be2, Wout, bout, out);
}

// Round 2
// 670.297 us; speedup vs baseline: 1.0704x; 1.0704x over previous
//
#include <hip/hip_runtime.h>
#include <math.h>

#define NN 100000
#define EE 1600000
#define HH 128
#define DX 64
#define CC 8
#define EPSV 1e-5f

#define CHUNK 512
#define NSCAN ((NN + CHUNK - 1) / CHUNK)   // 196

typedef unsigned int u32;
typedef unsigned short u16;

__device__ __forceinline__ float bf2f(u16 h) {
    u32 u = ((u32)h) << 16;
    union { u32 u; float f; } c; c.u = u; return c.f;
}
__device__ __forceinline__ u16 f2b(float f) {
    union { float f; u32 u; } c; c.f = f;
    u32 r = (c.u + 0x7fffu + ((c.u >> 16) & 1u)) >> 16;
    return (u16)r;
}

// ---------------- graph preprocessing ----------------

__global__ void k_zero(int* __restrict__ cnt, float* __restrict__ stats) {
    int i = blockIdx.x * blockDim.x + threadIdx.x;
    if (i < NN) cnt[i] = 0;
    if (i < 512) stats[i] = 0.f;
}

__global__ void k_count(const int* __restrict__ dst, int* __restrict__ cnt) {
    int e = blockIdx.x * blockDim.x + threadIdx.x;
    if (e < EE) atomicAdd(&cnt[dst[e]], 1);
}

__global__ void k_part(const int* __restrict__ cnt, int* __restrict__ part,
                       float* __restrict__ dinv) {
    __shared__ int ls[256];
    int b = blockIdx.x, t = threadIdx.x;
    int base = b * CHUNK;
    int s = 0;
    for (int i = t; i < CHUNK; i += 256) {
        int idx = base + i;
        if (idx < NN) {
            int c = cnt[idx];
            s += c;
            dinv[idx] = rsqrtf(1.0f + (float)c);
        }
    }
    ls[t] = s; __syncthreads();
    for (int d = 128; d > 0; d >>= 1) {
        if (t < d) ls[t] += ls[t + d];
        __syncthreads();
    }
    if (t == 0) part[b] = ls[0];
}

__global__ void k_scanpart(int* __restrict__ part) {
    __shared__ int ls[256];
    int t = threadIdx.x;
    int v = (t < NSCAN) ? part[t] : 0;
    ls[t] = v; __syncthreads();
    for (int d = 1; d < 256; d <<= 1) {
        int x = (t >= d) ? ls[t - d] : 0;
        __syncthreads();
        ls[t] += x;
        __syncthreads();
    }
    if (t < NSCAN) part[t] = ls[t] - v;   // exclusive
}

__global__ void k_scanchunk(const int* __restrict__ cnt, const int* __restrict__ part,
                            int* __restrict__ row_ptr, int* __restrict__ cursor) {
    __shared__ int ls[CHUNK];
    int b = blockIdx.x, t = threadIdx.x;
    int idx = b * CHUNK + t;
    int v = (idx < NN) ? cnt[idx] : 0;
    ls[t] = v; __syncthreads();
    for (int d = 1; d < CHUNK; d <<= 1) {
        int x = (t >= d) ? ls[t - d] : 0;
        __syncthreads();
        ls[t] += x;
        __syncthreads();
    }
    if (idx < NN) {
        int excl = part[b] + ls[t] - v;
        row_ptr[idx] = excl;
        cursor[idx] = excl;
    }
}

__global__ void k_scatter(const int* __restrict__ src, const int* __restrict__ dst,
                          int* __restrict__ cursor, int* __restrict__ col) {
    int e = blockIdx.x * blockDim.x + threadIdx.x;
    if (e < EE) {
        int d = dst[e];
        int pos = atomicAdd(&cursor[d], 1);
        col[pos] = src[e];
    }
}

__global__ void k_cvec(const float* __restrict__ sctx, const float* __restrict__ W1,
                       float* __restrict__ cvec) {
    int f = threadIdx.x;  // 128 threads
    float s = 0.f;
    #pragma unroll
    for (int j = 0; j < 64; ++j) s += sctx[j] * W1[(64 + j) * HH + f];
    cvec[f] = s;
}

// ---------------- GEMM1: hlin(bf16) = x @ W1[0:64,:] + cvec ----------------

__global__ __launch_bounds__(256) void k_gemm1(const float* __restrict__ x,
                                               const float* __restrict__ W1,
                                               const float* __restrict__ cvec,
                                               u16* __restrict__ hlin) {
    __shared__ float hsT[32][64];
    __shared__ float Wt[32][128];
    int t = threadIdx.x;
    int n0 = blockIdx.x * 64;
    int tc = t & 15, tr = t >> 4;
    int f0 = tc * 8, r0 = tr * 4;
    float acc[4][8];
    #pragma unroll
    for (int i = 0; i < 4; ++i)
        #pragma unroll
        for (int j = 0; j < 8; ++j) acc[i][j] = 0.f;

    for (int kc = 0; kc < DX; kc += 32) {
        #pragma unroll
        for (int l = 0; l < 2; ++l) {
            int idx = t + l * 256;
            int r = idx >> 3;
            int kq = idx & 7;
            int n = n0 + r;
            float4 v = make_float4(0.f, 0.f, 0.f, 0.f);
            if (n < NN) v = *(const float4*)&x[(size_t)n * DX + kc + kq * 4];
            hsT[kq * 4 + 0][r] = v.x;
            hsT[kq * 4 + 1][r] = v.y;
            hsT[kq * 4 + 2][r] = v.z;
            hsT[kq * 4 + 3][r] = v.w;
        }
        #pragma unroll
        for (int l = 0; l < 4; ++l) {
            int idx = t + l * 256;
            int k = idx >> 5;
            int f4 = idx & 31;
            *(float4*)&Wt[k][f4 * 4] = *(const float4*)&W1[(size_t)(kc + k) * HH + f4 * 4];
        }
        __syncthreads();
        #pragma unroll
        for (int k = 0; k < 32; ++k) {
            float4 hv = *(float4*)&hsT[k][r0];
            float4 w0 = *(float4*)&Wt[k][f0];
            float4 w1 = *(float4*)&Wt[k][f0 + 4];
            float h_[4] = {hv.x, hv.y, hv.z, hv.w};
            float w_[8] = {w0.x, w0.y, w0.z, w0.w, w1.x, w1.y, w1.z, w1.w};
            #pragma unroll
            for (int i = 0; i < 4; ++i)
                #pragma unroll
                for (int j = 0; j < 8; ++j) acc[i][j] = fmaf(h_[i], w_[j], acc[i][j]);
        }
        __syncthreads();
    }
    #pragma unroll
    for (int i = 0; i < 4; ++i) {
        int n = n0 + r0 + i;
        if (n < NN) {
            float o[8];
            #pragma unroll
            for (int j = 0; j < 8; ++j) o[j] = acc[i][j] + cvec[f0 + j];
            uint4 pk;
            pk.x = (u32)f2b(o[0]) | ((u32)f2b(o[1]) << 16);
            pk.y = (u32)f2b(o[2]) | ((u32)f2b(o[3]) << 16);
            pk.z = (u32)f2b(o[4]) | ((u32)f2b(o[5]) << 16);
            pk.w = (u32)f2b(o[6]) | ((u32)f2b(o[7]) << 16);
            *(uint4*)&hlin[(size_t)n * HH + f0] = pk;
        }
    }
}

// ---------------- GEMM2: hlin(bf16) = relu(bn1(hbuf)) @ W2 ----------------

__global__ __launch_bounds__(256) void k_gemm2(const u16* __restrict__ hin,
                                               const float* __restrict__ W2,
                                               const float* __restrict__ stats,
                                               const float* __restrict__ g,
                                               const float* __restrict__ be,
                                               u16* __restrict__ hlin) {
    __shared__ float hsT[32][64];
    __shared__ float Wt[32][128];
    __shared__ float asc[128], csc[128];
    int t = threadIdx.x;
    if (t < 128) {
        float mu  = stats[t] * (1.0f / NN);
        float var = stats[128 + t] * (1.0f / NN) - mu * mu;
        float rs  = rsqrtf(var + EPSV);
        float a   = g[t] * rs;
        asc[t] = a;
        csc[t] = be[t] - mu * a;
    }
    __syncthreads();

    int n0 = blockIdx.x * 64;
    int tc = t & 15, tr = t >> 4;
    int f0 = tc * 8, r0 = tr * 4;
    float acc[4][8];
    #pragma unroll
    for (int i = 0; i < 4; ++i)
        #pragma unroll
        for (int j = 0; j < 8; ++j) acc[i][j] = 0.f;

    int sr = t >> 2;       // 0..63 row
    int skg = t & 3;       // group of 8 k
    for (int kc = 0; kc < HH; kc += 32) {
        {
            int n = n0 + sr;
            uint4 v = make_uint4(0, 0, 0, 0);
            if (n < NN) v = *(const uint4*)&hin[(size_t)n * HH + kc + skg * 8];
            int kk = kc + skg * 8;
            u32 w[4] = {v.x, v.y, v.z, v.w};
            #pragma unroll
            for (int q = 0; q < 4; ++q) {
                float a0 = bf2f((u16)(w[q] & 0xffff));
                float a1 = bf2f((u16)(w[q] >> 16));
                hsT[skg * 8 + q * 2 + 0][sr] = fmaxf(fmaf(a0, asc[kk + q * 2 + 0], csc[kk + q * 2 + 0]), 0.f);
                hsT[skg * 8 + q * 2 + 1][sr] = fmaxf(fmaf(a1, asc[kk + q * 2 + 1], csc[kk + q * 2 + 1]), 0.f);
            }
        }
        #pragma unroll
        for (int l = 0; l < 4; ++l) {
            int idx = t + l * 256;
            int k = idx >> 5;
            int f4 = idx & 31;
            *(float4*)&Wt[k][f4 * 4] = *(const float4*)&W2[(size_t)(kc + k) * HH + f4 * 4];
        }
        __syncthreads();
        #pragma unroll
        for (int k = 0; k < 32; ++k) {
            float4 hv = *(float4*)&hsT[k][r0];
            float4 w0 = *(float4*)&Wt[k][f0];
            float4 w1 = *(float4*)&Wt[k][f0 + 4];
            float h_[4] = {hv.x, hv.y, hv.z, hv.w};
            float w_[8] = {w0.x, w0.y, w0.z, w0.w, w1.x, w1.y, w1.z, w1.w};
            #pragma unroll
            for (int i = 0; i < 4; ++i)
                #pragma unroll
                for (int j = 0; j < 8; ++j) acc[i][j] = fmaf(h_[i], w_[j], acc[i][j]);
        }
        __syncthreads();
    }
    #pragma unroll
    for (int i = 0; i < 4; ++i) {
        int n = n0 + r0 + i;
        if (n < NN) {
            uint4 pk;
            pk.x = (u32)f2b(acc[i][0]) | ((u32)f2b(acc[i][1]) << 16);
            pk.y = (u32)f2b(acc[i][2]) | ((u32)f2b(acc[i][3]) << 16);
            pk.z = (u32)f2b(acc[i][4]) | ((u32)f2b(acc[i][5]) << 16);
            pk.w = (u32)f2b(acc[i][6]) | ((u32)f2b(acc[i][7]) << 16);
            *(uint4*)&hlin[(size_t)n * HH + f0] = pk;
        }
    }
}

// ---------------- SpMM: hout(bf16) = relu(A @ hlin + self + b) ----------------
// one wave per node; half-wave per edge; lane handles 4 features (bf16x4 = 8B)

__global__ __launch_bounds__(256) void k_spmm(const u16* __restrict__ hlin,
                                              const int* __restrict__ row_ptr,
                                              const int* __restrict__ cnt,
                                              const int* __restrict__ col,
                                              const float* __restrict__ dinv,
                                              const float* __restrict__ b,
                                              u16* __restrict__ hout) {
    int wave = threadIdx.x >> 6;
    int lane = threadIdx.x & 63;
    int n = blockIdx.x * 4 + wave;
    if (n >= NN) return;
    int half = lane >> 5;
    int li = lane & 31;
    int f0 = li * 4;
    float dn = dinv[n];
    float a0, a1, a2, a3;
    {
        uint2 r = *(const uint2*)&hlin[(size_t)n * HH + f0];
        float sc = half ? 0.f : dn * dn;
        a0 = sc * bf2f((u16)(r.x & 0xffff));
        a1 = sc * bf2f((u16)(r.x >> 16));
        a2 = sc * bf2f((u16)(r.y & 0xffff));
        a3 = sc * bf2f((u16)(r.y >> 16));
    }
    int start = row_ptr[n], len = cnt[n];
    #pragma unroll 2
    for (int j = 0; j < len; j += 2) {
        int c0 = col[start + j];
        int c1 = (j + 1 < len) ? col[start + j + 1] : c0;
        int jj = j + half;
        bool v = jj < len;
        int s = half ? c1 : c0;
        s = v ? s : n;
        float nr = v ? dinv[s] * dn : 0.f;
        uint2 r = *(const uint2*)&hlin[(size_t)s * HH + f0];
        a0 = fmaf(bf2f((u16)(r.x & 0xffff)), nr, a0);
        a1 = fmaf(bf2f((u16)(r.x >> 16)),    nr, a1);
        a2 = fmaf(bf2f((u16)(r.y & 0xffff)), nr, a2);
        a3 = fmaf(bf2f((u16)(r.y >> 16)),    nr, a3);
    }
    a0 += __shfl_xor(a0, 32);
    a1 += __shfl_xor(a1, 32);
    a2 += __shfl_xor(a2, 32);
    a3 += __shfl_xor(a3, 32);
    if (!half) {
        float4 bb = *(const float4*)&b[f0];
        a0 = fmaxf(a0 + bb.x, 0.f);
        a1 = fmaxf(a1 + bb.y, 0.f);
        a2 = fmaxf(a2 + bb.z, 0.f);
        a3 = fmaxf(a3 + bb.w, 0.f);
        uint2 pk;
        pk.x = (u32)f2b(a0) | ((u32)f2b(a1) << 16);
        pk.y = (u32)f2b(a2) | ((u32)f2b(a3) << 16);
        *(uint2*)&hout[(size_t)n * HH + f0] = pk;
    }
}

// ---------------- BN stats: per-feature sum & sumsq (bf16 input) ----------------

__global__ __launch_bounds__(256) void k_stats(const u16* __restrict__ h,
                                               float* __restrict__ sums) {
    __shared__ float4 ls[4][64];
    int t = threadIdx.x;
    int lane = t & 63, wave = t >> 6;
    int f0 = lane * 2;
    float s0 = 0.f, s1 = 0.f, q0 = 0.f, q1 = 0.f;
    for (int row = blockIdx.x * 4 + wave; row < NN; row += gridDim.x * 4) {
        u32 v = *(const u32*)&h[(size_t)row * HH + f0];
        float a = bf2f((u16)(v & 0xffff));
        float c = bf2f((u16)(v >> 16));
        s0 += a; q0 += a * a;
        s1 += c; q1 += c * c;
    }
    ls[wave][lane] = make_float4(s0, s1, q0, q1);
    __syncthreads();
    if (wave == 0) {
        float4 r0 = ls[0][lane], r1 = ls[1][lane], r2 = ls[2][lane], r3 = ls[3][lane];
        atomicAdd(&sums[f0 + 0], r0.x + r1.x + r2.x + r3.x);
        atomicAdd(&sums[f0 + 1], r0.y + r1.y + r2.y + r3.y);
        atomicAdd(&sums[128 + f0 + 0], r0.z + r1.z + r2.z + r3.z);
        atomicAdd(&sums[128 + f0 + 1], r0.w + r1.w + r2.w + r3.w);
    }
}

// ---------------- output head: out = relu(bn2(h)) @ Wout + bout ----------------

__global__ __launch_bounds__(256) void k_out(const u16* __restrict__ h,
                                             const float* __restrict__ stats,
                                             const float* __restrict__ g,
                                             const float* __restrict__ be,
                                             const float* __restrict__ Wout,
                                             const float* __restrict__ bout,
                                             float* __restrict__ out) {
    __shared__ float hs[32][132];
    __shared__ float Wl[128][8];
    __shared__ float asc[128], csc[128];
    int t = threadIdx.x;
    if (t < 128) {
        float mu  = stats[256 + t] * (1.0f / NN);
        float var = stats[384 + t] * (1.0f / NN) - mu * mu;
        float rs  = rsqrtf(var + EPSV);
        float a   = g[t] * rs;
        asc[t] = a;
        csc[t] = be[t] - mu * a;
    }
    #pragma unroll
    for (int l = 0; l < 4; ++l) {
        int idx = t + l * 256;
        Wl[idx >> 3][idx & 7] = Wout[idx];
    }
    __syncthreads();

    int n0 = blockIdx.x * 32;
    #pragma unroll
    for (int l = 0; l < 2; ++l) {
        int idx = t + l * 256;         // 512 uint4 loads = 4096 bf16
        int r = idx >> 4;
        int kg = idx & 15;
        uint4 v = *(const uint4*)&h[(size_t)(n0 + r) * HH + kg * 8];
        u32 w[4] = {v.x, v.y, v.z, v.w};
        int kk = kg * 8;
        #pragma unroll
        for (int q = 0; q < 4; ++q) {
            float x0 = bf2f((u16)(w[q] & 0xffff));
            float x1 = bf2f((u16)(w[q] >> 16));
            hs[r][kk + q * 2 + 0] = fmaxf(fmaf(x0, asc[kk + q * 2 + 0], csc[kk + q * 2 + 0]), 0.f);
            hs[r][kk + q * 2 + 1] = fmaxf(fmaf(x1, asc[kk + q * 2 + 1], csc[kk + q * 2 + 1]), 0.f);
        }
    }
    __syncthreads();

    int c = t & 7, rl = t >> 3;
    float acc = 0.f;
    #pragma unroll 8
    for (int k = 0; k < 128; ++k) acc = fmaf(hs[rl][k], Wl[k][c], acc);
    out[(size_t)(n0 + rl) * CC + c] = acc + bout[c];
}

// ---------------- launch ----------------

extern "C" void kernel_launch(void* const* d_in, const int* in_sizes, int n_in,
                              void* d_out, int out_size, void* d_ws, size_t ws_size,
                              hipStream_t stream) {
    const float* x    = (const float*)d_in[0];
    const int*   src  = (const int*)d_in[1];
    const int*   dst  = (const int*)d_in[2];
    const float* sctx = (const float*)d_in[3];
    const float* W1   = (const float*)d_in[4];
    const float* b1   = (const float*)d_in[5];
    const float* g1   = (const float*)d_in[6];
    const float* be1  = (const float*)d_in[7];
    const float* W2   = (const float*)d_in[8];
    const float* b2   = (const float*)d_in[9];
    const float* g2   = (const float*)d_in[10];
    const float* be2  = (const float*)d_in[11];
    const float* Wout = (const float*)d_in[12];
    const float* bout = (const float*)d_in[13];
    float* out = (float*)d_out;

    char* p = (char*)d_ws;
    auto carve = [&](size_t bytes) -> char* {
        char* r = p;
        p += (bytes + 255) & ~(size_t)255;
        return r;
    };
    u16*   hlin   = (u16*)carve((size_t)NN * HH * 2);
    u16*   hbuf   = (u16*)carve((size_t)NN * HH * 2);
    int*   col    = (int*)carve((size_t)EE * 4 + 16);
    int*   cnt    = (int*)carve((size_t)NN * 4);
    int*   rowp   = (int*)carve((size_t)NN * 4);
    int*   cursor = (int*)carve((size_t)NN * 4);
    float* dinv   = (float*)carve((size_t)NN * 4);
    int*   part   = (int*)carve((size_t)NSCAN * 4);
    float* cvec   = (float*)carve(128 * 4);
    float* stats  = (float*)carve(512 * 4);

    k_zero<<<391, 256, 0, stream>>>(cnt, stats);
    k_count<<<(EE + 255) / 256, 256, 0, stream>>>(dst, cnt);
    k_part<<<NSCAN, 256, 0, stream>>>(cnt, part, dinv);
    k_scanpart<<<1, 256, 0, stream>>>(part);
    k_scanchunk<<<NSCAN, 512, 0, stream>>>(cnt, part, rowp, cursor);
    k_scatter<<<(EE + 255) / 256, 256, 0, stream>>>(src, dst, cursor, col);
    k_cvec<<<1, 128, 0, stream>>>(sctx, W1, cvec);

    k_gemm1<<<(NN + 63) / 64, 256, 0, stream>>>(x, W1, cvec, hlin);
    k_spmm<<<(NN + 3) / 4, 256, 0, stream>>>(hlin, rowp, cnt, col, dinv, b1, hbuf);
    k_stats<<<512, 256, 0, stream>>>(hbuf, stats);

    k_gemm2<<<(NN + 63) / 64, 256, 0, stream>>>(hbuf, W2, stats, g1, be1, hlin);
    k_spmm<<<(NN + 3) / 4, 256, 0, stream>>>(hlin, rowp, cnt, col, dinv, b2, hbuf);
    k_stats<<<512, 256, 0, stream>>>(hbuf, stats + 256);

    k_out<<<NN / 32, 256, 0, stream>>>(hbuf, stats, g2, be2, Wout, bout, out);
}

// Round 3
// 423.339 us; speedup vs baseline: 1.6948x; 1.5834x over previous
//
#include <hip/hip_runtime.h>
#include <math.h>

#define NN 100000
#define EE 1600000
#define HH 128
#define DX 64
#define CC 8
#define EPSV 1e-5f

#define CHUNK 512
#define NSCAN ((NN + CHUNK - 1) / CHUNK)   // 196

typedef unsigned int u32;
typedef unsigned short u16;
typedef __attribute__((ext_vector_type(8))) short short8v;   // 8 bf16 = 4 VGPR
typedef __attribute__((ext_vector_type(4))) float float4v;

__device__ __forceinline__ float bf2f(u16 h) {
    u32 u = ((u32)h) << 16;
    union { u32 u; float f; } c; c.u = u; return c.f;
}
__device__ __forceinline__ u16 f2b(float f) {
    union { float f; u32 u; } c; c.f = f;
    u32 r = (c.u + 0x7fffu + ((c.u >> 16) & 1u)) >> 16;
    return (u16)r;
}

// ---------------- graph preprocessing ----------------

__global__ void k_zero(int* __restrict__ cnt, float* __restrict__ stats) {
    int i = blockIdx.x * blockDim.x + threadIdx.x;
    if (i < NN) cnt[i] = 0;
    if (i < 512) stats[i] = 0.f;
}

__global__ void k_count(const int* __restrict__ dst, int* __restrict__ cnt) {
    int e = blockIdx.x * blockDim.x + threadIdx.x;
    if (e < EE) atomicAdd(&cnt[dst[e]], 1);
}

__global__ void k_part(const int* __restrict__ cnt, int* __restrict__ part,
                       float* __restrict__ dinv) {
    __shared__ int ls[256];
    int b = blockIdx.x, t = threadIdx.x;
    int base = b * CHUNK;
    int s = 0;
    for (int i = t; i < CHUNK; i += 256) {
        int idx = base + i;
        if (idx < NN) {
            int c = cnt[idx];
            s += c;
            dinv[idx] = rsqrtf(1.0f + (float)c);
        }
    }
    ls[t] = s; __syncthreads();
    for (int d = 128; d > 0; d >>= 1) {
        if (t < d) ls[t] += ls[t + d];
        __syncthreads();
    }
    if (t == 0) part[b] = ls[0];
}

__global__ void k_scanpart(int* __restrict__ part) {
    __shared__ int ls[256];
    int t = threadIdx.x;
    int v = (t < NSCAN) ? part[t] : 0;
    ls[t] = v; __syncthreads();
    for (int d = 1; d < 256; d <<= 1) {
        int x = (t >= d) ? ls[t - d] : 0;
        __syncthreads();
        ls[t] += x;
        __syncthreads();
    }
    if (t < NSCAN) part[t] = ls[t] - v;   // exclusive
}

__global__ void k_scanchunk(const int* __restrict__ cnt, const int* __restrict__ part,
                            int* __restrict__ row_ptr, int* __restrict__ cursor) {
    __shared__ int ls[CHUNK];
    int b = blockIdx.x, t = threadIdx.x;
    int idx = b * CHUNK + t;
    int v = (idx < NN) ? cnt[idx] : 0;
    ls[t] = v; __syncthreads();
    for (int d = 1; d < CHUNK; d <<= 1) {
        int x = (t >= d) ? ls[t - d] : 0;
        __syncthreads();
        ls[t] += x;
        __syncthreads();
    }
    if (idx < NN) {
        int excl = part[b] + ls[t] - v;
        row_ptr[idx] = excl;
        cursor[idx] = excl;
    }
}

// scatter edges as (src, weight) records; weight = dinv[src]*dinv[dst]
__global__ void k_scatter(const int* __restrict__ src, const int* __restrict__ dst,
                          const float* __restrict__ dinv,
                          int* __restrict__ cursor, int2* __restrict__ ew) {
    int e = blockIdx.x * blockDim.x + threadIdx.x;
    if (e < EE) {
        int d = dst[e];
        int s = src[e];
        int pos = atomicAdd(&cursor[d], 1);
        float w = dinv[s] * dinv[d];
        ew[pos] = make_int2(s, __float_as_int(w));
    }
}

__global__ void k_cvec(const float* __restrict__ sctx, const float* __restrict__ W1,
                       float* __restrict__ cvec) {
    int f = threadIdx.x;  // 128 threads
    float s = 0.f;
    #pragma unroll
    for (int j = 0; j < 64; ++j) s += sctx[j] * W1[(64 + j) * HH + f];
    cvec[f] = s;
}

// transpose+cast weights: Bt1[col][k] (128x64) from W1[0:64], Bt2[col][k] (128x128) from W2
__global__ void k_trans(const float* __restrict__ W1, const float* __restrict__ W2,
                        u16* __restrict__ Bt1, u16* __restrict__ Bt2) {
    int i = blockIdx.x * 256 + threadIdx.x;     // 96 blocks * 256 = 24576
    if (i < 128 * 64) {
        int col = i >> 6, k = i & 63;
        Bt1[i] = f2b(W1[(size_t)k * HH + col]);
    } else if (i < 128 * 64 + 128 * 128) {
        int j = i - 128 * 64;
        int col = j >> 7, k = j & 127;
        Bt2[j] = f2b(W2[(size_t)k * HH + col]);
    }
}

// ---------------- MFMA GEMM1: hlin(bf16) = bf16(x) @ W1[0:64,:] + cvec ----------------
// block: 256 thr = 4 waves; tile 64 rows x 128 cols; K=64

__global__ __launch_bounds__(256) void k_mgemm1(const float* __restrict__ x,
                                                const u16* __restrict__ Bt1,
                                                const float* __restrict__ cvec,
                                                u16* __restrict__ outp) {
    __shared__ u16 As[64 * 64];     // 8KB, row stride 128B, swizzled
    __shared__ u16 Bs[128 * 64];    // 16KB, col-major [col][k], swizzled; reused as Cs
    __shared__ float cvs[128];
    int t = threadIdx.x;
    int n0 = blockIdx.x * 64;
    if (t < 128) cvs[t] = cvec[t];

    // stage B: 8192 elems = 1024 uint4
    #pragma unroll
    for (int l = 0; l < 4; ++l) {
        int idx = t + l * 256;
        int col = idx >> 3, kg = idx & 7;
        uint4 v = *(const uint4*)&Bt1[idx * 8];
        u32 byte = (u32)(col * 128 + kg * 16) ^ ((col & 7) << 4);
        *(uint4*)((char*)Bs + byte) = v;
    }
    // stage A: 64 rows x 64 f fp32 -> bf16
    #pragma unroll
    for (int l = 0; l < 4; ++l) {
        int idx = t + l * 256;
        int r = idx >> 4, fg = idx & 15;
        int n = n0 + r; if (n > NN - 1) n = NN - 1;
        float4 v = *(const float4*)&x[(size_t)n * DX + fg * 4];
        u32 lo = (u32)f2b(v.x) | ((u32)f2b(v.y) << 16);
        u32 hi = (u32)f2b(v.z) | ((u32)f2b(v.w) << 16);
        u32 byte = (u32)(r * 128 + fg * 8) ^ ((r & 7) << 4);
        *(uint2*)((char*)As + byte) = make_uint2(lo, hi);
    }
    __syncthreads();

    int w = t >> 6, lane = t & 63;
    int rl = lane & 15, kq = lane >> 4;
    int rbase = w * 16 + rl;
    float4v acc[8];
    #pragma unroll
    for (int nt = 0; nt < 8; ++nt) acc[nt] = (float4v){0.f, 0.f, 0.f, 0.f};

    #pragma unroll
    for (int kk = 0; kk < 2; ++kk) {
        u32 ab = (u32)(rbase * 128 + kk * 64 + kq * 16) ^ ((rbase & 7) << 4);
        short8v af = *(const short8v*)((const char*)As + ab);
        #pragma unroll
        for (int nt = 0; nt < 8; ++nt) {
            int col = nt * 16 + rl;
            u32 bb = (u32)(col * 128 + kk * 64 + kq * 16) ^ ((col & 7) << 4);
            short8v bf = *(const short8v*)((const char*)Bs + bb);
            acc[nt] = __builtin_amdgcn_mfma_f32_16x16x32_bf16(af, bf, acc[nt], 0, 0, 0);
        }
    }
    __syncthreads();
    // epilogue: acc -> Cs (=Bs, 64x128 bf16 swizzled)
    #pragma unroll
    for (int nt = 0; nt < 8; ++nt) {
        int col = nt * 16 + rl;
        #pragma unroll
        for (int j = 0; j < 4; ++j) {
            int row = w * 16 + kq * 4 + j;
            u16 v = f2b(acc[nt][j] + cvs[col]);
            u32 byte = (u32)(row * 256 + col * 2) ^ ((row & 7) << 4);
            *(u16*)((char*)Bs + byte) = v;
        }
    }
    __syncthreads();
    #pragma unroll
    for (int l = 0; l < 4; ++l) {
        int idx = t + l * 256;
        int r = idx >> 4, kg = idx & 15;
        u32 byte = (u32)(r * 256 + kg * 16) ^ ((r & 7) << 4);
        uint4 v = *(const uint4*)((const char*)Bs + byte);
        int n = n0 + r;
        if (n < NN) *(uint4*)&outp[(size_t)n * HH + kg * 8] = v;
    }
}

// ---------------- MFMA GEMM2: hlin(bf16) = relu(bn1(hbuf)) @ W2 ----------------

__global__ __launch_bounds__(256) void k_mgemm2(const u16* __restrict__ hin,
                                                const u16* __restrict__ Bt2,
                                                const float* __restrict__ stats,
                                                const float* __restrict__ g,
                                                const float* __restrict__ be,
                                                u16* __restrict__ outp) {
    __shared__ u16 As[64 * 128];    // 16KB, row stride 256B, swizzled; reused as Cs
    __shared__ u16 Bs[128 * 128];   // 32KB, [col][k], swizzled
    __shared__ float asc[128], csc[128];
    int t = threadIdx.x;
    int n0 = blockIdx.x * 64;
    if (t < 128) {
        float mu  = stats[t] * (1.0f / NN);
        float var = stats[128 + t] * (1.0f / NN) - mu * mu;
        float rs  = rsqrtf(var + EPSV);
        float a   = g[t] * rs;
        asc[t] = a;
        csc[t] = be[t] - mu * a;
    }
    // stage B: 16384 elems = 2048 uint4
    #pragma unroll
    for (int l = 0; l < 8; ++l) {
        int idx = t + l * 256;
        int col = idx >> 4, kg = idx & 15;
        uint4 v = *(const uint4*)&Bt2[idx * 8];
        u32 byte = (u32)(col * 256 + kg * 16) ^ ((col & 7) << 4);
        *(uint4*)((char*)Bs + byte) = v;
    }
    __syncthreads();   // asc/csc ready
    // stage A with bn+relu: 64 rows x 128
    #pragma unroll
    for (int l = 0; l < 4; ++l) {
        int idx = t + l * 256;
        int r = idx >> 4, kg = idx & 15;
        int n = n0 + r; if (n > NN - 1) n = NN - 1;
        uint4 v = *(const uint4*)&hin[(size_t)n * HH + kg * 8];
        u32 wds[4] = {v.x, v.y, v.z, v.w};
        u32 pk[2][2];
        #pragma unroll
        for (int q = 0; q < 4; ++q) {
            int k = kg * 8 + q * 2;
            float x0 = bf2f((u16)(wds[q] & 0xffff));
            float x1 = bf2f((u16)(wds[q] >> 16));
            u16 o0 = f2b(fmaxf(fmaf(x0, asc[k],     csc[k]),     0.f));
            u16 o1 = f2b(fmaxf(fmaf(x1, asc[k + 1], csc[k + 1]), 0.f));
            pk[q >> 1][q & 1] = (u32)o0 | ((u32)o1 << 16);
        }
        uint4 ov = make_uint4(pk[0][0], pk[0][1], pk[1][0], pk[1][1]);
        u32 byte = (u32)(r * 256 + kg * 16) ^ ((r & 7) << 4);
        *(uint4*)((char*)As + byte) = ov;
    }
    __syncthreads();

    int w = t >> 6, lane = t & 63;
    int rl = lane & 15, kq = lane >> 4;
    int rbase = w * 16 + rl;
    float4v acc[8];
    #pragma unroll
    for (int nt = 0; nt < 8; ++nt) acc[nt] = (float4v){0.f, 0.f, 0.f, 0.f};

    #pragma unroll
    for (int kk = 0; kk < 4; ++kk) {
        u32 ab = (u32)(rbase * 256 + kk * 64 + kq * 16) ^ ((rbase & 7) << 4);
        short8v af = *(const short8v*)((const char*)As + ab);
        #pragma unroll
        for (int nt = 0; nt < 8; ++nt) {
            int col = nt * 16 + rl;
            u32 bb = (u32)(col * 256 + kk * 64 + kq * 16) ^ ((col & 7) << 4);
            short8v bf = *(const short8v*)((const char*)Bs + bb);
            acc[nt] = __builtin_amdgcn_mfma_f32_16x16x32_bf16(af, bf, acc[nt], 0, 0, 0);
        }
    }
    __syncthreads();
    #pragma unroll
    for (int nt = 0; nt < 8; ++nt) {
        int col = nt * 16 + rl;
        #pragma unroll
        for (int j = 0; j < 4; ++j) {
            int row = w * 16 + kq * 4 + j;
            u16 v = f2b(acc[nt][j]);
            u32 byte = (u32)(row * 256 + col * 2) ^ ((row & 7) << 4);
            *(u16*)((char*)As + byte) = v;
        }
    }
    __syncthreads();
    #pragma unroll
    for (int l = 0; l < 4; ++l) {
        int idx = t + l * 256;
        int r = idx >> 4, kg = idx & 15;
        u32 byte = (u32)(r * 256 + kg * 16) ^ ((r & 7) << 4);
        uint4 v = *(const uint4*)((const char*)As + byte);
        int n = n0 + r;
        if (n < NN) *(uint4*)&outp[(size_t)n * HH + kg * 8] = v;
    }
}

// ---------------- SpMM: hout(bf16) = relu(A @ hlin + self + b) ----------------
// wave per node; quarter-wave (16 lanes) per edge -> 4 edges in flight;
// lane covers 8 features (16B); edge weights precomputed.

__global__ __launch_bounds__(256) void k_spmm(const u16* __restrict__ hlin,
                                              const int* __restrict__ row_ptr,
                                              const int* __restrict__ cnt,
                                              const int2* __restrict__ ew,
                                              const float* __restrict__ dinv,
                                              const float* __restrict__ b,
                                              u16* __restrict__ hout) {
    int wave = threadIdx.x >> 6;
    int lane = threadIdx.x & 63;
    int n = blockIdx.x * 4 + wave;          // grid exact: 25000 blocks
    int q = lane >> 4, li = lane & 15;
    int f0 = li * 8;
    float dn = dinv[n];
    float a[8];
    {
        uint4 r = *(const uint4*)&hlin[(size_t)n * HH + f0];
        float sc = (q == 0) ? dn * dn : 0.f;
        u32 wd[4] = {r.x, r.y, r.z, r.w};
        #pragma unroll
        for (int j = 0; j < 4; ++j) {
            a[j * 2 + 0] = sc * bf2f((u16)(wd[j] & 0xffff));
            a[j * 2 + 1] = sc * bf2f((u16)(wd[j] >> 16));
        }
    }
    int start = row_ptr[n], len = cnt[n];
    #pragma unroll 2
    for (int j = q; j < len; j += 4) {
        int2 e = ew[start + j];
        float wv = __int_as_float(e.y);
        uint4 r = *(const uint4*)&hlin[(size_t)e.x * HH + f0];
        u32 wd[4] = {r.x, r.y, r.z, r.w};
        #pragma unroll
        for (int k = 0; k < 4; ++k) {
            a[k * 2 + 0] = fmaf(bf2f((u16)(wd[k] & 0xffff)), wv, a[k * 2 + 0]);
            a[k * 2 + 1] = fmaf(bf2f((u16)(wd[k] >> 16)),    wv, a[k * 2 + 1]);
        }
    }
    #pragma unroll
    for (int k = 0; k < 8; ++k) {
        a[k] += __shfl_xor(a[k], 16);
        a[k] += __shfl_xor(a[k], 32);
    }
    if (q == 0) {
        float4 b0 = *(const float4*)&b[f0];
        float4 b1 = *(const float4*)&b[f0 + 4];
        float bb[8] = {b0.x, b0.y, b0.z, b0.w, b1.x, b1.y, b1.z, b1.w};
        uint4 pk;
        u32 o[4];
        #pragma unroll
        for (int k = 0; k < 4; ++k) {
            float v0 = fmaxf(a[k * 2 + 0] + bb[k * 2 + 0], 0.f);
            float v1 = fmaxf(a[k * 2 + 1] + bb[k * 2 + 1], 0.f);
            o[k] = (u32)f2b(v0) | ((u32)f2b(v1) << 16);
        }
        pk = make_uint4(o[0], o[1], o[2], o[3]);
        *(uint4*)&hout[(size_t)n * HH + f0] = pk;
    }
}

// ---------------- BN stats: per-feature sum & sumsq (bf16 input) ----------------

__global__ __launch_bounds__(256) void k_stats(const u16* __restrict__ h,
                                               float* __restrict__ sums) {
    __shared__ float4 ls[4][64];
    int t = threadIdx.x;
    int lane = t & 63, wave = t >> 6;
    int f0 = lane * 2;
    float s0 = 0.f, s1 = 0.f, q0 = 0.f, q1 = 0.f;
    for (int row = blockIdx.x * 4 + wave; row < NN; row += gridDim.x * 4) {
        u32 v = *(const u32*)&h[(size_t)row * HH + f0];
        float a = bf2f((u16)(v & 0xffff));
        float c = bf2f((u16)(v >> 16));
        s0 += a; q0 += a * a;
        s1 += c; q1 += c * c;
    }
    ls[wave][lane] = make_float4(s0, s1, q0, q1);
    __syncthreads();
    if (wave == 0) {
        float4 r0 = ls[0][lane], r1 = ls[1][lane], r2 = ls[2][lane], r3 = ls[3][lane];
        atomicAdd(&sums[f0 + 0], r0.x + r1.x + r2.x + r3.x);
        atomicAdd(&sums[f0 + 1], r0.y + r1.y + r2.y + r3.y);
        atomicAdd(&sums[128 + f0 + 0], r0.z + r1.z + r2.z + r3.z);
        atomicAdd(&sums[128 + f0 + 1], r0.w + r1.w + r2.w + r3.w);
    }
}

// ---------------- output head: out = relu(bn2(h)) @ Wout + bout ----------------

__global__ __launch_bounds__(256) void k_out(const u16* __restrict__ h,
                                             const float* __restrict__ stats,
                                             const float* __restrict__ g,
                                             const float* __restrict__ be,
                                             const float* __restrict__ Wout,
                                             const float* __restrict__ bout,
                                             float* __restrict__ out) {
    __shared__ float hs[32][132];
    __shared__ float Wl[128][8];
    __shared__ float asc[128], csc[128];
    int t = threadIdx.x;
    if (t < 128) {
        float mu  = stats[256 + t] * (1.0f / NN);
        float var = stats[384 + t] * (1.0f / NN) - mu * mu;
        float rs  = rsqrtf(var + EPSV);
        float a   = g[t] * rs;
        asc[t] = a;
        csc[t] = be[t] - mu * a;
    }
    #pragma unroll
    for (int l = 0; l < 4; ++l) {
        int idx = t + l * 256;
        Wl[idx >> 3][idx & 7] = Wout[idx];
    }
    __syncthreads();

    int n0 = blockIdx.x * 32;
    #pragma unroll
    for (int l = 0; l < 2; ++l) {
        int idx = t + l * 256;
        int r = idx >> 4;
        int kg = idx & 15;
        uint4 v = *(const uint4*)&h[(size_t)(n0 + r) * HH + kg * 8];
        u32 w[4] = {v.x, v.y, v.z, v.w};
        int kk = kg * 8;
        #pragma unroll
        for (int qq = 0; qq < 4; ++qq) {
            float x0 = bf2f((u16)(w[qq] & 0xffff));
            float x1 = bf2f((u16)(w[qq] >> 16));
            hs[r][kk + qq * 2 + 0] = fmaxf(fmaf(x0, asc[kk + qq * 2 + 0], csc[kk + qq * 2 + 0]), 0.f);
            hs[r][kk + qq * 2 + 1] = fmaxf(fmaf(x1, asc[kk + qq * 2 + 1], csc[kk + qq * 2 + 1]), 0.f);
        }
    }
    __syncthreads();

    int c = t & 7, rl = t >> 3;
    float acc = 0.f;
    #pragma unroll 8
    for (int k = 0; k < 128; ++k) acc = fmaf(hs[rl][k], Wl[k][c], acc);
    out[(size_t)(n0 + rl) * CC + c] = acc + bout[c];
}

// ---------------- launch ----------------

extern "C" void kernel_launch(void* const* d_in, const int* in_sizes, int n_in,
                              void* d_out, int out_size, void* d_ws, size_t ws_size,
                              hipStream_t stream) {
    const float* x    = (const float*)d_in[0];
    const int*   src  = (const int*)d_in[1];
    const int*   dst  = (const int*)d_in[2];
    const float* sctx = (const float*)d_in[3];
    const float* W1   = (const float*)d_in[4];
    const float* b1   = (const float*)d_in[5];
    const float* g1   = (const float*)d_in[6];
    const float* be1  = (const float*)d_in[7];
    const float* W2   = (const float*)d_in[8];
    const float* b2   = (const float*)d_in[9];
    const float* g2   = (const float*)d_in[10];
    const float* be2  = (const float*)d_in[11];
    const float* Wout = (const float*)d_in[12];
    const float* bout = (const float*)d_in[13];
    float* out = (float*)d_out;

    char* p = (char*)d_ws;
    auto carve = [&](size_t bytes) -> char* {
        char* r = p;
        p += (bytes + 255) & ~(size_t)255;
        return r;
    };
    u16*   hlin   = (u16*)carve((size_t)NN * HH * 2);
    u16*   hbuf   = (u16*)carve((size_t)NN * HH * 2);
    int2*  ew     = (int2*)carve((size_t)EE * 8 + 16);
    int*   cnt    = (int*)carve((size_t)NN * 4);
    int*   rowp   = (int*)carve((size_t)NN * 4);
    int*   cursor = (int*)carve((size_t)NN * 4);
    float* dinv   = (float*)carve((size_t)NN * 4);
    int*   part   = (int*)carve((size_t)NSCAN * 4);
    float* cvec   = (float*)carve(128 * 4);
    float* stats  = (float*)carve(512 * 4);
    u16*   Bt1    = (u16*)carve(128 * 64 * 2);
    u16*   Bt2    = (u16*)carve(128 * 128 * 2);

    k_zero<<<391, 256, 0, stream>>>(cnt, stats);
    k_count<<<(EE + 255) / 256, 256, 0, stream>>>(dst, cnt);
    k_part<<<NSCAN, 256, 0, stream>>>(cnt, part, dinv);
    k_scanpart<<<1, 256, 0, stream>>>(part);
    k_scanchunk<<<NSCAN, 512, 0, stream>>>(cnt, part, rowp, cursor);
    k_scatter<<<(EE + 255) / 256, 256, 0, stream>>>(src, dst, dinv, cursor, ew);
    k_cvec<<<1, 128, 0, stream>>>(sctx, W1, cvec);
    k_trans<<<96, 256, 0, stream>>>(W1, W2, Bt1, Bt2);

    k_mgemm1<<<(NN + 63) / 64, 256, 0, stream>>>(x, Bt1, cvec, hlin);
    k_spmm<<<NN / 4, 256, 0, stream>>>(hlin, rowp, cnt, ew, dinv, b1, hbuf);
    k_stats<<<512, 256, 0, stream>>>(hbuf, stats);

    k_mgemm2<<<(NN + 63) / 64, 256, 0, stream>>>(hbuf, Bt2, stats, g1, be1, hlin);
    k_spmm<<<NN / 4, 256, 0, stream>>>(hlin, rowp, cnt, ew, dinv, b2, hbuf);
    k_stats<<<512, 256, 0, stream>>>(hbuf, stats + 256);

    k_out<<<NN / 32, 256, 0, stream>>>(hbuf, stats, g2, be2, Wout, bout, out);
}

// Round 4
// 399.540 us; speedup vs baseline: 1.7957x; 1.0596x over previous
//
#include <hip/hip_runtime.h>
#include <math.h>

#define NN 100000
#define EE 1600000
#define HH 128
#define DX 64
#define CC 8
#define EPSV 1e-5f

#define CHUNK 512
#define NSCAN ((NN + CHUNK - 1) / CHUNK)   // 196

#define NB 782          // ceil(NN/128) coarse buckets of 128 nodes
#define EPB 4096        // edges per k_bin block
#define NBLK_BIN ((EE + EPB - 1) / EPB)    // 391

typedef unsigned int u32;
typedef unsigned short u16;
typedef __attribute__((ext_vector_type(8))) short short8v;   // 8 bf16 = 4 VGPR
typedef __attribute__((ext_vector_type(4))) float float4v;

__device__ __forceinline__ float bf2f(u16 h) {
    u32 u = ((u32)h) << 16;
    union { u32 u; float f; } c; c.u = u; return c.f;
}
__device__ __forceinline__ u16 f2b(float f) {
    union { float f; u32 u; } c; c.f = f;
    u32 r = (c.u + 0x7fffu + ((c.u >> 16) & 1u)) >> 16;
    return (u16)r;
}

// ---------------- graph preprocessing ----------------

__global__ void k_zero(int* __restrict__ cnt, float* __restrict__ stats) {
    int i = blockIdx.x * blockDim.x + threadIdx.x;
    if (i < NN) cnt[i] = 0;
    if (i < 512) stats[i] = 0.f;
}

__global__ void k_count(const int* __restrict__ dst, int* __restrict__ cnt) {
    int e = blockIdx.x * blockDim.x + threadIdx.x;
    if (e < EE) atomicAdd(&cnt[dst[e]], 1);
}

__global__ void k_part(const int* __restrict__ cnt, int* __restrict__ part,
                       float* __restrict__ dinv) {
    __shared__ int ls[256];
    int b = blockIdx.x, t = threadIdx.x;
    int base = b * CHUNK;
    int s = 0;
    for (int i = t; i < CHUNK; i += 256) {
        int idx = base + i;
        if (idx < NN) {
            int c = cnt[idx];
            s += c;
            dinv[idx] = rsqrtf(1.0f + (float)c);
        }
    }
    ls[t] = s; __syncthreads();
    for (int d = 128; d > 0; d >>= 1) {
        if (t < d) ls[t] += ls[t + d];
        __syncthreads();
    }
    if (t == 0) part[b] = ls[0];
}

__global__ void k_scanpart(int* __restrict__ part) {
    __shared__ int ls[256];
    int t = threadIdx.x;
    int v = (t < NSCAN) ? part[t] : 0;
    ls[t] = v; __syncthreads();
    for (int d = 1; d < 256; d <<= 1) {
        int x = (t >= d) ? ls[t - d] : 0;
        __syncthreads();
        ls[t] += x;
        __syncthreads();
    }
    if (t < NSCAN) part[t] = ls[t] - v;   // exclusive
}

__global__ void k_scanchunk(const int* __restrict__ cnt, const int* __restrict__ part,
                            int* __restrict__ row_ptr) {
    __shared__ int ls[CHUNK];
    int b = blockIdx.x, t = threadIdx.x;
    int idx = b * CHUNK + t;
    int v = (idx < NN) ? cnt[idx] : 0;
    ls[t] = v; __syncthreads();
    for (int d = 1; d < CHUNK; d <<= 1) {
        int x = (t >= d) ? ls[t - d] : 0;
        __syncthreads();
        ls[t] += x;
        __syncthreads();
    }
    if (idx < NN) row_ptr[idx] = part[b] + ls[t] - v;
}

// init per-bucket global cursors to bucket base = rowp[b*128]
__global__ void k_binit(const int* __restrict__ rowp, int* __restrict__ gcursor) {
    int b = blockIdx.x * blockDim.x + threadIdx.x;
    if (b < NB) gcursor[b] = rowp[b << 7];
}

// phase B: LDS-binned scatter into coarse bucket regions (contiguous runs)
__global__ __launch_bounds__(256) void k_bin(const int* __restrict__ src,
                                             const int* __restrict__ dst,
                                             int* __restrict__ gcursor,
                                             u32* __restrict__ tmp) {
    __shared__ u32 rec[EPB];              // 16 KB
    __shared__ int bcnt[NB], lstart[NB], gbase[NB], bofs[NB];
    __shared__ int part[256];
    int t = threadIdx.x;
    int e0 = blockIdx.x * EPB;
    for (int i = t; i < NB; i += 256) { bcnt[i] = 0; bofs[i] = 0; }
    __syncthreads();
    int myd[16];
    #pragma unroll
    for (int i = 0; i < 16; ++i) {
        int e = e0 + t + i * 256;
        int d = (e < EE) ? dst[e] : -1;
        myd[i] = d;
        if (d >= 0) atomicAdd(&bcnt[d >> 7], 1);
    }
    __syncthreads();
    // exclusive scan of bcnt (NB entries): thread owns 4
    int base = t * 4;
    int c0 = 0, c1 = 0, c2 = 0, c3 = 0;
    if (base < NB)     c0 = bcnt[base];
    if (base + 1 < NB) c1 = bcnt[base + 1];
    if (base + 2 < NB) c2 = bcnt[base + 2];
    if (base + 3 < NB) c3 = bcnt[base + 3];
    int tot = c0 + c1 + c2 + c3;
    part[t] = tot; __syncthreads();
    for (int d = 1; d < 256; d <<= 1) {
        int x = (t >= d) ? part[t - d] : 0;
        __syncthreads();
        part[t] += x;
        __syncthreads();
    }
    int ex = part[t] - tot;
    if (base < NB)     { lstart[base]     = ex;               if (c0) gbase[base]     = atomicAdd(&gcursor[base],     c0); }
    if (base + 1 < NB) { lstart[base + 1] = ex + c0;          if (c1) gbase[base + 1] = atomicAdd(&gcursor[base + 1], c1); }
    if (base + 2 < NB) { lstart[base + 2] = ex + c0 + c1;     if (c2) gbase[base + 2] = atomicAdd(&gcursor[base + 2], c2); }
    if (base + 3 < NB) { lstart[base + 3] = ex + c0 + c1 + c2; if (c3) gbase[base + 3] = atomicAdd(&gcursor[base + 3], c3); }
    __syncthreads();
    // local scatter into grouped LDS
    #pragma unroll
    for (int i = 0; i < 16; ++i) {
        int d = myd[i];
        if (d >= 0) {
            int e = e0 + t + i * 256;
            int s = src[e];
            int b = d >> 7;
            int lp = atomicAdd(&bofs[b], 1);
            rec[lstart[b] + lp] = (u32)s | ((u32)(d & 127) << 17);
        }
    }
    __syncthreads();
    // flush grouped runs to global bucket regions
    for (int b = t; b < NB; b += 256) {
        int n = bcnt[b];
        if (n) {
            int gb = gbase[b], ls = lstart[b];
            for (int j = 0; j < n; ++j) tmp[gb + j] = rec[ls + j];
        }
    }
}

// phase C: per-bucket exact CSR placement + weight compute
__global__ __launch_bounds__(256) void k_csr(const u32* __restrict__ tmp,
                                             const int* __restrict__ rowp,
                                             const float* __restrict__ dinv,
                                             int2* __restrict__ ew) {
    __shared__ int lcur[128];
    __shared__ float ldin[128];
    int b = blockIdx.x, t = threadIdx.x;
    int n0 = b << 7;
    if (t < 128) {
        int n = n0 + t;
        lcur[t] = (n < NN) ? rowp[n] : 0;
        ldin[t] = (n < NN) ? dinv[n] : 0.f;
    }
    __syncthreads();
    int beg = rowp[n0];
    int end = (n0 + 128 < NN) ? rowp[n0 + 128] : EE;
    for (int i = beg + t; i < end; i += 256) {
        u32 r = tmp[i];
        int s = r & 0x1FFFF;
        int dl = r >> 17;
        int pos = atomicAdd(&lcur[dl], 1);
        float w = dinv[s] * ldin[dl];
        ew[pos] = make_int2(s, __float_as_int(w));
    }
}

__global__ void k_cvec(const float* __restrict__ sctx, const float* __restrict__ W1,
                       float* __restrict__ cvec) {
    int f = threadIdx.x;  // 128 threads
    float s = 0.f;
    #pragma unroll
    for (int j = 0; j < 64; ++j) s += sctx[j] * W1[(64 + j) * HH + f];
    cvec[f] = s;
}

// transpose+cast weights: Bt1[col][k] (128x64) from W1[0:64], Bt2[col][k] (128x128) from W2
__global__ void k_trans(const float* __restrict__ W1, const float* __restrict__ W2,
                        u16* __restrict__ Bt1, u16* __restrict__ Bt2) {
    int i = blockIdx.x * 256 + threadIdx.x;     // 96 blocks * 256 = 24576
    if (i < 128 * 64) {
        int col = i >> 6, k = i & 63;
        Bt1[i] = f2b(W1[(size_t)k * HH + col]);
    } else if (i < 128 * 64 + 128 * 128) {
        int j = i - 128 * 64;
        int col = j >> 7, k = j & 127;
        Bt2[j] = f2b(W2[(size_t)k * HH + col]);
    }
}

// ---------------- MFMA GEMM1: hlin(bf16) = bf16(x) @ W1[0:64,:] + cvec ----------------

__global__ __launch_bounds__(256) void k_mgemm1(const float* __restrict__ x,
                                                const u16* __restrict__ Bt1,
                                                const float* __restrict__ cvec,
                                                u16* __restrict__ outp) {
    __shared__ u16 As[64 * 64];
    __shared__ u16 Bs[128 * 64];
    __shared__ float cvs[128];
    int t = threadIdx.x;
    int n0 = blockIdx.x * 64;
    if (t < 128) cvs[t] = cvec[t];

    #pragma unroll
    for (int l = 0; l < 4; ++l) {
        int idx = t + l * 256;
        int col = idx >> 3, kg = idx & 7;
        uint4 v = *(const uint4*)&Bt1[idx * 8];
        u32 byte = (u32)(col * 128 + kg * 16) ^ ((col & 7) << 4);
        *(uint4*)((char*)Bs + byte) = v;
    }
    #pragma unroll
    for (int l = 0; l < 4; ++l) {
        int idx = t + l * 256;
        int r = idx >> 4, fg = idx & 15;
        int n = n0 + r; if (n > NN - 1) n = NN - 1;
        float4 v = *(const float4*)&x[(size_t)n * DX + fg * 4];
        u32 lo = (u32)f2b(v.x) | ((u32)f2b(v.y) << 16);
        u32 hi = (u32)f2b(v.z) | ((u32)f2b(v.w) << 16);
        u32 byte = (u32)(r * 128 + fg * 8) ^ ((r & 7) << 4);
        *(uint2*)((char*)As + byte) = make_uint2(lo, hi);
    }
    __syncthreads();

    int w = t >> 6, lane = t & 63;
    int rl = lane & 15, kq = lane >> 4;
    int rbase = w * 16 + rl;
    float4v acc[8];
    #pragma unroll
    for (int nt = 0; nt < 8; ++nt) acc[nt] = (float4v){0.f, 0.f, 0.f, 0.f};

    #pragma unroll
    for (int kk = 0; kk < 2; ++kk) {
        u32 ab = (u32)(rbase * 128 + kk * 64 + kq * 16) ^ ((rbase & 7) << 4);
        short8v af = *(const short8v*)((const char*)As + ab);
        #pragma unroll
        for (int nt = 0; nt < 8; ++nt) {
            int col = nt * 16 + rl;
            u32 bb = (u32)(col * 128 + kk * 64 + kq * 16) ^ ((col & 7) << 4);
            short8v bf = *(const short8v*)((const char*)Bs + bb);
            acc[nt] = __builtin_amdgcn_mfma_f32_16x16x32_bf16(af, bf, acc[nt], 0, 0, 0);
        }
    }
    __syncthreads();
    #pragma unroll
    for (int nt = 0; nt < 8; ++nt) {
        int col = nt * 16 + rl;
        #pragma unroll
        for (int j = 0; j < 4; ++j) {
            int row = w * 16 + kq * 4 + j;
            u16 v = f2b(acc[nt][j] + cvs[col]);
            u32 byte = (u32)(row * 256 + col * 2) ^ ((row & 7) << 4);
            *(u16*)((char*)Bs + byte) = v;
        }
    }
    __syncthreads();
    #pragma unroll
    for (int l = 0; l < 4; ++l) {
        int idx = t + l * 256;
        int r = idx >> 4, kg = idx & 15;
        u32 byte = (u32)(r * 256 + kg * 16) ^ ((r & 7) << 4);
        uint4 v = *(const uint4*)((const char*)Bs + byte);
        int n = n0 + r;
        if (n < NN) *(uint4*)&outp[(size_t)n * HH + kg * 8] = v;
    }
}

// ---------------- MFMA GEMM2: hlin(bf16) = relu(bn1(hbuf)) @ W2 ----------------

__global__ __launch_bounds__(256) void k_mgemm2(const u16* __restrict__ hin,
                                                const u16* __restrict__ Bt2,
                                                const float* __restrict__ stats,
                                                const float* __restrict__ g,
                                                const float* __restrict__ be,
                                                u16* __restrict__ outp) {
    __shared__ u16 As[64 * 128];
    __shared__ u16 Bs[128 * 128];
    __shared__ float asc[128], csc[128];
    int t = threadIdx.x;
    int n0 = blockIdx.x * 64;
    if (t < 128) {
        float mu  = stats[t] * (1.0f / NN);
        float var = stats[128 + t] * (1.0f / NN) - mu * mu;
        float rs  = rsqrtf(var + EPSV);
        float a   = g[t] * rs;
        asc[t] = a;
        csc[t] = be[t] - mu * a;
    }
    #pragma unroll
    for (int l = 0; l < 8; ++l) {
        int idx = t + l * 256;
        int col = idx >> 4, kg = idx & 15;
        uint4 v = *(const uint4*)&Bt2[idx * 8];
        u32 byte = (u32)(col * 256 + kg * 16) ^ ((col & 7) << 4);
        *(uint4*)((char*)Bs + byte) = v;
    }
    __syncthreads();
    #pragma unroll
    for (int l = 0; l < 4; ++l) {
        int idx = t + l * 256;
        int r = idx >> 4, kg = idx & 15;
        int n = n0 + r; if (n > NN - 1) n = NN - 1;
        uint4 v = *(const uint4*)&hin[(size_t)n * HH + kg * 8];
        u32 wds[4] = {v.x, v.y, v.z, v.w};
        u32 pk[2][2];
        #pragma unroll
        for (int q = 0; q < 4; ++q) {
            int k = kg * 8 + q * 2;
            float x0 = bf2f((u16)(wds[q] & 0xffff));
            float x1 = bf2f((u16)(wds[q] >> 16));
            u16 o0 = f2b(fmaxf(fmaf(x0, asc[k],     csc[k]),     0.f));
            u16 o1 = f2b(fmaxf(fmaf(x1, asc[k + 1], csc[k + 1]), 0.f));
            pk[q >> 1][q & 1] = (u32)o0 | ((u32)o1 << 16);
        }
        uint4 ov = make_uint4(pk[0][0], pk[0][1], pk[1][0], pk[1][1]);
        u32 byte = (u32)(r * 256 + kg * 16) ^ ((r & 7) << 4);
        *(uint4*)((char*)As + byte) = ov;
    }
    __syncthreads();

    int w = t >> 6, lane = t & 63;
    int rl = lane & 15, kq = lane >> 4;
    int rbase = w * 16 + rl;
    float4v acc[8];
    #pragma unroll
    for (int nt = 0; nt < 8; ++nt) acc[nt] = (float4v){0.f, 0.f, 0.f, 0.f};

    #pragma unroll
    for (int kk = 0; kk < 4; ++kk) {
        u32 ab = (u32)(rbase * 256 + kk * 64 + kq * 16) ^ ((rbase & 7) << 4);
        short8v af = *(const short8v*)((const char*)As + ab);
        #pragma unroll
        for (int nt = 0; nt < 8; ++nt) {
            int col = nt * 16 + rl;
            u32 bb = (u32)(col * 256 + kk * 64 + kq * 16) ^ ((col & 7) << 4);
            short8v bf = *(const short8v*)((const char*)Bs + bb);
            acc[nt] = __builtin_amdgcn_mfma_f32_16x16x32_bf16(af, bf, acc[nt], 0, 0, 0);
        }
    }
    __syncthreads();
    #pragma unroll
    for (int nt = 0; nt < 8; ++nt) {
        int col = nt * 16 + rl;
        #pragma unroll
        for (int j = 0; j < 4; ++j) {
            int row = w * 16 + kq * 4 + j;
            u16 v = f2b(acc[nt][j]);
            u32 byte = (u32)(row * 256 + col * 2) ^ ((row & 7) << 4);
            *(u16*)((char*)As + byte) = v;
        }
    }
    __syncthreads();
    #pragma unroll
    for (int l = 0; l < 4; ++l) {
        int idx = t + l * 256;
        int r = idx >> 4, kg = idx & 15;
        u32 byte = (u32)(r * 256 + kg * 16) ^ ((r & 7) << 4);
        uint4 v = *(const uint4*)((const char*)As + byte);
        int n = n0 + r;
        if (n < NN) *(uint4*)&outp[(size_t)n * HH + kg * 8] = v;
    }
}

// ---------------- SpMM: hout(bf16) = relu(A @ hlin + self + b) ----------------

__global__ __launch_bounds__(256) void k_spmm(const u16* __restrict__ hlin,
                                              const int* __restrict__ row_ptr,
                                              const int* __restrict__ cnt,
                                              const int2* __restrict__ ew,
                                              const float* __restrict__ dinv,
                                              const float* __restrict__ b,
                                              u16* __restrict__ hout) {
    int wave = threadIdx.x >> 6;
    int lane = threadIdx.x & 63;
    int n = blockIdx.x * 4 + wave;
    int q = lane >> 4, li = lane & 15;
    int f0 = li * 8;
    float dn = dinv[n];
    float a[8];
    {
        uint4 r = *(const uint4*)&hlin[(size_t)n * HH + f0];
        float sc = (q == 0) ? dn * dn : 0.f;
        u32 wd[4] = {r.x, r.y, r.z, r.w};
        #pragma unroll
        for (int j = 0; j < 4; ++j) {
            a[j * 2 + 0] = sc * bf2f((u16)(wd[j] & 0xffff));
            a[j * 2 + 1] = sc * bf2f((u16)(wd[j] >> 16));
        }
    }
    int start = row_ptr[n], len = cnt[n];
    #pragma unroll 4
    for (int j = q; j < len; j += 4) {
        int2 e = ew[start + j];
        float wv = __int_as_float(e.y);
        uint4 r = *(const uint4*)&hlin[(size_t)e.x * HH + f0];
        u32 wd[4] = {r.x, r.y, r.z, r.w};
        #pragma unroll
        for (int k = 0; k < 4; ++k) {
            a[k * 2 + 0] = fmaf(bf2f((u16)(wd[k] & 0xffff)), wv, a[k * 2 + 0]);
            a[k * 2 + 1] = fmaf(bf2f((u16)(wd[k] >> 16)),    wv, a[k * 2 + 1]);
        }
    }
    #pragma unroll
    for (int k = 0; k < 8; ++k) {
        a[k] += __shfl_xor(a[k], 16);
        a[k] += __shfl_xor(a[k], 32);
    }
    if (q == 0) {
        float4 b0 = *(const float4*)&b[f0];
        float4 b1 = *(const float4*)&b[f0 + 4];
        float bb[8] = {b0.x, b0.y, b0.z, b0.w, b1.x, b1.y, b1.z, b1.w};
        u32 o[4];
        #pragma unroll
        for (int k = 0; k < 4; ++k) {
            float v0 = fmaxf(a[k * 2 + 0] + bb[k * 2 + 0], 0.f);
            float v1 = fmaxf(a[k * 2 + 1] + bb[k * 2 + 1], 0.f);
            o[k] = (u32)f2b(v0) | ((u32)f2b(v1) << 16);
        }
        uint4 pk = make_uint4(o[0], o[1], o[2], o[3]);
        *(uint4*)&hout[(size_t)n * HH + f0] = pk;
    }
}

// ---------------- BN stats ----------------

__global__ __launch_bounds__(256) void k_stats(const u16* __restrict__ h,
                                               float* __restrict__ sums) {
    __shared__ float4 ls[4][64];
    int t = threadIdx.x;
    int lane = t & 63, wave = t >> 6;
    int f0 = lane * 2;
    float s0 = 0.f, s1 = 0.f, q0 = 0.f, q1 = 0.f;
    for (int row = blockIdx.x * 4 + wave; row < NN; row += gridDim.x * 4) {
        u32 v = *(const u32*)&h[(size_t)row * HH + f0];
        float a = bf2f((u16)(v & 0xffff));
        float c = bf2f((u16)(v >> 16));
        s0 += a; q0 += a * a;
        s1 += c; q1 += c * c;
    }
    ls[wave][lane] = make_float4(s0, s1, q0, q1);
    __syncthreads();
    if (wave == 0) {
        float4 r0 = ls[0][lane], r1 = ls[1][lane], r2 = ls[2][lane], r3 = ls[3][lane];
        atomicAdd(&sums[f0 + 0], r0.x + r1.x + r2.x + r3.x);
        atomicAdd(&sums[f0 + 1], r0.y + r1.y + r2.y + r3.y);
        atomicAdd(&sums[128 + f0 + 0], r0.z + r1.z + r2.z + r3.z);
        atomicAdd(&sums[128 + f0 + 1], r0.w + r1.w + r2.w + r3.w);
    }
}

// ---------------- output head ----------------

__global__ __launch_bounds__(256) void k_out(const u16* __restrict__ h,
                                             const float* __restrict__ stats,
                                             const float* __restrict__ g,
                                             const float* __restrict__ be,
                                             const float* __restrict__ Wout,
                                             const float* __restrict__ bout,
                                             float* __restrict__ out) {
    __shared__ float hs[32][132];
    __shared__ float Wl[128][8];
    __shared__ float asc[128], csc[128];
    int t = threadIdx.x;
    if (t < 128) {
        float mu  = stats[256 + t] * (1.0f / NN);
        float var = stats[384 + t] * (1.0f / NN) - mu * mu;
        float rs  = rsqrtf(var + EPSV);
        float a   = g[t] * rs;
        asc[t] = a;
        csc[t] = be[t] - mu * a;
    }
    #pragma unroll
    for (int l = 0; l < 4; ++l) {
        int idx = t + l * 256;
        Wl[idx >> 3][idx & 7] = Wout[idx];
    }
    __syncthreads();

    int n0 = blockIdx.x * 32;
    #pragma unroll
    for (int l = 0; l < 2; ++l) {
        int idx = t + l * 256;
        int r = idx >> 4;
        int kg = idx & 15;
        uint4 v = *(const uint4*)&h[(size_t)(n0 + r) * HH + kg * 8];
        u32 w[4] = {v.x, v.y, v.z, v.w};
        int kk = kg * 8;
        #pragma unroll
        for (int qq = 0; qq < 4; ++qq) {
            float x0 = bf2f((u16)(w[qq] & 0xffff));
            float x1 = bf2f((u16)(w[qq] >> 16));
            hs[r][kk + qq * 2 + 0] = fmaxf(fmaf(x0, asc[kk + qq * 2 + 0], csc[kk + qq * 2 + 0]), 0.f);
            hs[r][kk + qq * 2 + 1] = fmaxf(fmaf(x1, asc[kk + qq * 2 + 1], csc[kk + qq * 2 + 1]), 0.f);
        }
    }
    __syncthreads();

    int c = t & 7, rl = t >> 3;
    float acc = 0.f;
    #pragma unroll 8
    for (int k = 0; k < 128; ++k) acc = fmaf(hs[rl][k], Wl[k][c], acc);
    out[(size_t)(n0 + rl) * CC + c] = acc + bout[c];
}

// ---------------- launch ----------------

extern "C" void kernel_launch(void* const* d_in, const int* in_sizes, int n_in,
                              void* d_out, int out_size, void* d_ws, size_t ws_size,
                              hipStream_t stream) {
    const float* x    = (const float*)d_in[0];
    const int*   src  = (const int*)d_in[1];
    const int*   dst  = (const int*)d_in[2];
    const float* sctx = (const float*)d_in[3];
    const float* W1   = (const float*)d_in[4];
    const float* b1   = (const float*)d_in[5];
    const float* g1   = (const float*)d_in[6];
    const float* be1  = (const float*)d_in[7];
    const float* W2   = (const float*)d_in[8];
    const float* b2   = (const float*)d_in[9];
    const float* g2   = (const float*)d_in[10];
    const float* be2  = (const float*)d_in[11];
    const float* Wout = (const float*)d_in[12];
    const float* bout = (const float*)d_in[13];
    float* out = (float*)d_out;

    char* p = (char*)d_ws;
    auto carve = [&](size_t bytes) -> char* {
        char* r = p;
        p += (bytes + 255) & ~(size_t)255;
        return r;
    };
    u16*   hlin    = (u16*)carve((size_t)NN * HH * 2);
    u16*   hbuf    = (u16*)carve((size_t)NN * HH * 2);
    int2*  ew      = (int2*)carve((size_t)EE * 8 + 16);
    u32*   tmp     = (u32*)carve((size_t)EE * 4 + 16);
    int*   cnt     = (int*)carve((size_t)NN * 4);
    int*   rowp    = (int*)carve((size_t)NN * 4);
    int*   gcursor = (int*)carve((size_t)NB * 4);
    float* dinv    = (float*)carve((size_t)NN * 4);
    int*   part    = (int*)carve((size_t)NSCAN * 4);
    float* cvec    = (float*)carve(128 * 4);
    float* stats   = (float*)carve(512 * 4);
    u16*   Bt1     = (u16*)carve(128 * 64 * 2);
    u16*   Bt2     = (u16*)carve(128 * 128 * 2);

    k_zero<<<391, 256, 0, stream>>>(cnt, stats);
    k_count<<<(EE + 255) / 256, 256, 0, stream>>>(dst, cnt);
    k_part<<<NSCAN, 256, 0, stream>>>(cnt, part, dinv);
    k_scanpart<<<1, 256, 0, stream>>>(part);
    k_scanchunk<<<NSCAN, 512, 0, stream>>>(cnt, part, rowp);
    k_binit<<<(NB + 255) / 256, 256, 0, stream>>>(rowp, gcursor);
    k_bin<<<NBLK_BIN, 256, 0, stream>>>(src, dst, gcursor, tmp);
    k_csr<<<NB, 256, 0, stream>>>(tmp, rowp, dinv, ew);
    k_cvec<<<1, 128, 0, stream>>>(sctx, W1, cvec);
    k_trans<<<96, 256, 0, stream>>>(W1, W2, Bt1, Bt2);

    k_mgemm1<<<(NN + 63) / 64, 256, 0, stream>>>(x, Bt1, cvec, hlin);
    k_spmm<<<NN / 4, 256, 0, stream>>>(hlin, rowp, cnt, ew, dinv, b1, hbuf);
    k_stats<<<512, 256, 0, stream>>>(hbuf, stats);

    k_mgemm2<<<(NN + 63) / 64, 256, 0, stream>>>(hbuf, Bt2, stats, g1, be1, hlin);
    k_spmm<<<NN / 4, 256, 0, stream>>>(hlin, rowp, cnt, ew, dinv, b2, hbuf);
    k_stats<<<512, 256, 0, stream>>>(hbuf, stats + 256);

    k_out<<<NN / 32, 256, 0, stream>>>(hbuf, stats, g2, be2, Wout, bout, out);
}

// Round 5
// 377.808 us; speedup vs baseline: 1.8990x; 1.0575x over previous
//
#include <hip/hip_runtime.h>
#include <math.h>

#define NN 100000
#define EE 1600000
#define HH 128
#define DX 64
#define CC 8
#define EPSV 1e-5f

#define CHUNK 512
#define NSCAN ((NN + CHUNK - 1) / CHUNK)   // 196

#define NB 782          // ceil(NN/128) coarse buckets of 128 nodes
#define BCAP 4096       // fixed tmp capacity per bucket (Poisson(2048), +45 sigma)
#define EPB 4096        // edges per k_bin block
#define NBLK_BIN ((EE + EPB - 1) / EPB)    // 391

typedef unsigned int u32;
typedef unsigned short u16;
typedef __attribute__((ext_vector_type(8))) short short8v;   // 8 bf16 = 4 VGPR
typedef __attribute__((ext_vector_type(4))) float float4v;

__device__ __forceinline__ float bf2f(u16 h) {
    u32 u = ((u32)h) << 16;
    union { u32 u; float f; } c; c.u = u; return c.f;
}
__device__ __forceinline__ u16 f2b(float f) {
    union { float f; u32 u; } c; c.f = f;
    u32 r = (c.u + 0x7fffu + ((c.u >> 16) & 1u)) >> 16;
    return (u16)r;
}

// ---------------- setup: zero counters, init bucket cursors ----------------

__global__ void k_zero(int* __restrict__ cnt, float* __restrict__ stats,
                       int* __restrict__ gcursor) {
    int i = blockIdx.x * blockDim.x + threadIdx.x;
    if (i < NN) cnt[i] = 0;
    if (i < 512) stats[i] = 0.f;
    if (i < NB) gcursor[i] = i * BCAP;
}

// cvec = scene_context @ W1[64:128,:]; Bt1/Bt2 = transposed bf16 weights
__global__ void k_prep(const float* __restrict__ sctx,
                       const float* __restrict__ W1, const float* __restrict__ W2,
                       float* __restrict__ cvec,
                       u16* __restrict__ Bt1, u16* __restrict__ Bt2) {
    int i = blockIdx.x * 256 + threadIdx.x;
    if (i < 128 * 64) {
        int col = i >> 6, k = i & 63;
        Bt1[i] = f2b(W1[(size_t)k * HH + col]);
    } else if (i < 128 * 64 + 128 * 128) {
        int j = i - 128 * 64;
        int col = j >> 7, k = j & 127;
        Bt2[j] = f2b(W2[(size_t)k * HH + col]);
    }
    if (blockIdx.x == 96 && threadIdx.x < 128) {
        int f = threadIdx.x;
        float s = 0.f;
        #pragma unroll
        for (int j = 0; j < 64; ++j) s += sctx[j] * W1[(64 + j) * HH + f];
        cvec[f] = s;
    }
}

// bin edges into fixed per-bucket regions of tmp; fused per-node degree count
__global__ __launch_bounds__(256) void k_bin(const int* __restrict__ src,
                                             const int* __restrict__ dst,
                                             int* __restrict__ cnt,
                                             int* __restrict__ gcursor,
                                             u32* __restrict__ tmp) {
    __shared__ int bcnt[NB], gbase[NB], bofs[NB];
    int t = threadIdx.x;
    int e0 = blockIdx.x * EPB;
    for (int i = t; i < NB; i += 256) { bcnt[i] = 0; bofs[i] = 0; }
    __syncthreads();
    int myd[16], mys[16];
    #pragma unroll
    for (int i = 0; i < 16; ++i) {
        int e = e0 + t + i * 256;
        int d = -1, s = 0;
        if (e < EE) {
            d = dst[e]; s = src[e];
            atomicAdd(&bcnt[d >> 7], 1);
            atomicAdd(&cnt[d], 1);
        }
        myd[i] = d; mys[i] = s;
    }
    __syncthreads();
    for (int b = t; b < NB; b += 256) {
        int c = bcnt[b];
        if (c) gbase[b] = atomicAdd(&gcursor[b], c);
    }
    __syncthreads();
    #pragma unroll
    for (int i = 0; i < 16; ++i) {
        int d = myd[i];
        if (d >= 0) {
            int b = d >> 7;
            int lp = atomicAdd(&bofs[b], 1);
            tmp[gbase[b] + lp] = (u32)mys[i] | ((u32)(d & 127) << 17);
        }
    }
}

__global__ void k_part(const int* __restrict__ cnt, int* __restrict__ part,
                       float* __restrict__ dinv) {
    __shared__ int ls[256];
    int b = blockIdx.x, t = threadIdx.x;
    int base = b * CHUNK;
    int s = 0;
    for (int i = t; i < CHUNK; i += 256) {
        int idx = base + i;
        if (idx < NN) {
            int c = cnt[idx];
            s += c;
            dinv[idx] = rsqrtf(1.0f + (float)c);
        }
    }
    ls[t] = s; __syncthreads();
    for (int d = 128; d > 0; d >>= 1) {
        if (t < d) ls[t] += ls[t + d];
        __syncthreads();
    }
    if (t == 0) part[b] = ls[0];
}

__global__ void k_scanpart(int* __restrict__ part) {
    __shared__ int ls[256];
    int t = threadIdx.x;
    int v = (t < NSCAN) ? part[t] : 0;
    ls[t] = v; __syncthreads();
    for (int d = 1; d < 256; d <<= 1) {
        int x = (t >= d) ? ls[t - d] : 0;
        __syncthreads();
        ls[t] += x;
        __syncthreads();
    }
    if (t < NSCAN) part[t] = ls[t] - v;   // exclusive
}

__global__ void k_scanchunk(const int* __restrict__ cnt, const int* __restrict__ part,
                            int* __restrict__ row_ptr) {
    __shared__ int ls[CHUNK];
    int b = blockIdx.x, t = threadIdx.x;
    int idx = b * CHUNK + t;
    int v = (idx < NN) ? cnt[idx] : 0;
    ls[t] = v; __syncthreads();
    for (int d = 1; d < CHUNK; d <<= 1) {
        int x = (t >= d) ? ls[t - d] : 0;
        __syncthreads();
        ls[t] += x;
        __syncthreads();
    }
    if (idx < NN) row_ptr[idx] = part[b] + ls[t] - v;
}

// per-bucket exact CSR placement + weight compute
__global__ __launch_bounds__(256) void k_csr(const u32* __restrict__ tmp,
                                             const int* __restrict__ gcursor,
                                             const int* __restrict__ rowp,
                                             const float* __restrict__ dinv,
                                             int2* __restrict__ ew) {
    __shared__ int lcur[128];
    __shared__ float ldin[128];
    int b = blockIdx.x, t = threadIdx.x;
    int n0 = b << 7;
    if (t < 128) {
        int n = n0 + t;
        lcur[t] = (n < NN) ? rowp[n] : 0;
        ldin[t] = (n < NN) ? dinv[n] : 0.f;
    }
    __syncthreads();
    int beg = b * BCAP;
    int end = gcursor[b];
    for (int i = beg + t; i < end; i += 256) {
        u32 r = tmp[i];
        int s = r & 0x1FFFF;
        int dl = (r >> 17) & 127;
        int pos = atomicAdd(&lcur[dl], 1);
        float w = dinv[s] * ldin[dl];
        ew[pos] = make_int2(s, __float_as_int(w));
    }
}

// ---------------- MFMA GEMM1: hlin(bf16) = bf16(x) @ W1[0:64,:] + cvec ----------------

__global__ __launch_bounds__(256) void k_mgemm1(const float* __restrict__ x,
                                                const u16* __restrict__ Bt1,
                                                const float* __restrict__ cvec,
                                                u16* __restrict__ outp) {
    __shared__ u16 As[64 * 64];
    __shared__ u16 Bs[128 * 64];
    __shared__ float cvs[128];
    int t = threadIdx.x;
    int n0 = blockIdx.x * 64;
    if (t < 128) cvs[t] = cvec[t];

    #pragma unroll
    for (int l = 0; l < 4; ++l) {
        int idx = t + l * 256;
        int col = idx >> 3, kg = idx & 7;
        uint4 v = *(const uint4*)&Bt1[idx * 8];
        u32 byte = (u32)(col * 128 + kg * 16) ^ ((col & 7) << 4);
        *(uint4*)((char*)Bs + byte) = v;
    }
    #pragma unroll
    for (int l = 0; l < 4; ++l) {
        int idx = t + l * 256;
        int r = idx >> 4, fg = idx & 15;
        int n = n0 + r; if (n > NN - 1) n = NN - 1;
        float4 v = *(const float4*)&x[(size_t)n * DX + fg * 4];
        u32 lo = (u32)f2b(v.x) | ((u32)f2b(v.y) << 16);
        u32 hi = (u32)f2b(v.z) | ((u32)f2b(v.w) << 16);
        u32 byte = (u32)(r * 128 + fg * 8) ^ ((r & 7) << 4);
        *(uint2*)((char*)As + byte) = make_uint2(lo, hi);
    }
    __syncthreads();

    int w = t >> 6, lane = t & 63;
    int rl = lane & 15, kq = lane >> 4;
    int rbase = w * 16 + rl;
    float4v acc[8];
    #pragma unroll
    for (int nt = 0; nt < 8; ++nt) acc[nt] = (float4v){0.f, 0.f, 0.f, 0.f};

    #pragma unroll
    for (int kk = 0; kk < 2; ++kk) {
        u32 ab = (u32)(rbase * 128 + kk * 64 + kq * 16) ^ ((rbase & 7) << 4);
        short8v af = *(const short8v*)((const char*)As + ab);
        #pragma unroll
        for (int nt = 0; nt < 8; ++nt) {
            int col = nt * 16 + rl;
            u32 bb = (u32)(col * 128 + kk * 64 + kq * 16) ^ ((col & 7) << 4);
            short8v bf = *(const short8v*)((const char*)Bs + bb);
            acc[nt] = __builtin_amdgcn_mfma_f32_16x16x32_bf16(af, bf, acc[nt], 0, 0, 0);
        }
    }
    __syncthreads();
    #pragma unroll
    for (int nt = 0; nt < 8; ++nt) {
        int col = nt * 16 + rl;
        #pragma unroll
        for (int j = 0; j < 4; ++j) {
            int row = w * 16 + kq * 4 + j;
            u16 v = f2b(acc[nt][j] + cvs[col]);
            u32 byte = (u32)(row * 256 + col * 2) ^ ((row & 7) << 4);
            *(u16*)((char*)Bs + byte) = v;
        }
    }
    __syncthreads();
    #pragma unroll
    for (int l = 0; l < 4; ++l) {
        int idx = t + l * 256;
        int r = idx >> 4, kg = idx & 15;
        u32 byte = (u32)(r * 256 + kg * 16) ^ ((r & 7) << 4);
        uint4 v = *(const uint4*)((const char*)Bs + byte);
        int n = n0 + r;
        if (n < NN) *(uint4*)&outp[(size_t)n * HH + kg * 8] = v;
    }
}

// ---------------- MFMA GEMM2: hlin(bf16) = relu(bn1(hbuf)) @ W2 ----------------

__global__ __launch_bounds__(256) void k_mgemm2(const u16* __restrict__ hin,
                                                const u16* __restrict__ Bt2,
                                                const float* __restrict__ stats,
                                                const float* __restrict__ g,
                                                const float* __restrict__ be,
                                                u16* __restrict__ outp) {
    __shared__ u16 As[64 * 128];
    __shared__ u16 Bs[128 * 128];
    __shared__ float asc[128], csc[128];
    int t = threadIdx.x;
    int n0 = blockIdx.x * 64;
    if (t < 128) {
        float mu  = stats[t] * (1.0f / NN);
        float var = stats[128 + t] * (1.0f / NN) - mu * mu;
        float rs  = rsqrtf(var + EPSV);
        float a   = g[t] * rs;
        asc[t] = a;
        csc[t] = be[t] - mu * a;
    }
    #pragma unroll
    for (int l = 0; l < 8; ++l) {
        int idx = t + l * 256;
        int col = idx >> 4, kg = idx & 15;
        uint4 v = *(const uint4*)&Bt2[idx * 8];
        u32 byte = (u32)(col * 256 + kg * 16) ^ ((col & 7) << 4);
        *(uint4*)((char*)Bs + byte) = v;
    }
    __syncthreads();
    #pragma unroll
    for (int l = 0; l < 4; ++l) {
        int idx = t + l * 256;
        int r = idx >> 4, kg = idx & 15;
        int n = n0 + r; if (n > NN - 1) n = NN - 1;
        uint4 v = *(const uint4*)&hin[(size_t)n * HH + kg * 8];
        u32 wds[4] = {v.x, v.y, v.z, v.w};
        u32 pk[2][2];
        #pragma unroll
        for (int q = 0; q < 4; ++q) {
            int k = kg * 8 + q * 2;
            float x0 = bf2f((u16)(wds[q] & 0xffff));
            float x1 = bf2f((u16)(wds[q] >> 16));
            u16 o0 = f2b(fmaxf(fmaf(x0, asc[k],     csc[k]),     0.f));
            u16 o1 = f2b(fmaxf(fmaf(x1, asc[k + 1], csc[k + 1]), 0.f));
            pk[q >> 1][q & 1] = (u32)o0 | ((u32)o1 << 16);
        }
        uint4 ov = make_uint4(pk[0][0], pk[0][1], pk[1][0], pk[1][1]);
        u32 byte = (u32)(r * 256 + kg * 16) ^ ((r & 7) << 4);
        *(uint4*)((char*)As + byte) = ov;
    }
    __syncthreads();

    int w = t >> 6, lane = t & 63;
    int rl = lane & 15, kq = lane >> 4;
    int rbase = w * 16 + rl;
    float4v acc[8];
    #pragma unroll
    for (int nt = 0; nt < 8; ++nt) acc[nt] = (float4v){0.f, 0.f, 0.f, 0.f};

    #pragma unroll
    for (int kk = 0; kk < 4; ++kk) {
        u32 ab = (u32)(rbase * 256 + kk * 64 + kq * 16) ^ ((rbase & 7) << 4);
        short8v af = *(const short8v*)((const char*)As + ab);
        #pragma unroll
        for (int nt = 0; nt < 8; ++nt) {
            int col = nt * 16 + rl;
            u32 bb = (u32)(col * 256 + kk * 64 + kq * 16) ^ ((col & 7) << 4);
            short8v bf = *(const short8v*)((const char*)Bs + bb);
            acc[nt] = __builtin_amdgcn_mfma_f32_16x16x32_bf16(af, bf, acc[nt], 0, 0, 0);
        }
    }
    __syncthreads();
    #pragma unroll
    for (int nt = 0; nt < 8; ++nt) {
        int col = nt * 16 + rl;
        #pragma unroll
        for (int j = 0; j < 4; ++j) {
            int row = w * 16 + kq * 4 + j;
            u16 v = f2b(acc[nt][j]);
            u32 byte = (u32)(row * 256 + col * 2) ^ ((row & 7) << 4);
            *(u16*)((char*)As + byte) = v;
        }
    }
    __syncthreads();
    #pragma unroll
    for (int l = 0; l < 4; ++l) {
        int idx = t + l * 256;
        int r = idx >> 4, kg = idx & 15;
        u32 byte = (u32)(r * 256 + kg * 16) ^ ((r & 7) << 4);
        uint4 v = *(const uint4*)((const char*)As + byte);
        int n = n0 + r;
        if (n < NN) *(uint4*)&outp[(size_t)n * HH + kg * 8] = v;
    }
}

// ---------------- SpMM + fused BN stats ----------------
// grid-stride; wave per node; quarter-wave per edge; q==0 lanes keep
// per-feature sum/sumsq in registers, block-reduced + atomically flushed.

__global__ __launch_bounds__(256) void k_spmm(const u16* __restrict__ hlin,
                                              const int* __restrict__ rowp,
                                              const int* __restrict__ cnt,
                                              const int2* __restrict__ ew,
                                              const float* __restrict__ dinv,
                                              const float* __restrict__ b,
                                              u16* __restrict__ hout,
                                              float* __restrict__ sums) {
    __shared__ float sacc[4][256];
    int t = threadIdx.x;
    int wave = t >> 6, lane = t & 63;
    int q = lane >> 4, li = lane & 15;
    int f0 = li * 8;
    float bb[8];
    {
        float4 b0 = *(const float4*)&b[f0];
        float4 b1 = *(const float4*)&b[f0 + 4];
        bb[0] = b0.x; bb[1] = b0.y; bb[2] = b0.z; bb[3] = b0.w;
        bb[4] = b1.x; bb[5] = b1.y; bb[6] = b1.z; bb[7] = b1.w;
    }
    float ss[8], s2[8];
    #pragma unroll
    for (int k = 0; k < 8; ++k) { ss[k] = 0.f; s2[k] = 0.f; }

    for (int n = blockIdx.x * 4 + wave; n < NN; n += gridDim.x * 4) {
        float dn = dinv[n];
        float a[8];
        {
            uint4 r = *(const uint4*)&hlin[(size_t)n * HH + f0];
            float sc = (q == 0) ? dn * dn : 0.f;
            u32 wd[4] = {r.x, r.y, r.z, r.w};
            #pragma unroll
            for (int j = 0; j < 4; ++j) {
                a[j * 2 + 0] = sc * bf2f((u16)(wd[j] & 0xffff));
                a[j * 2 + 1] = sc * bf2f((u16)(wd[j] >> 16));
            }
        }
        int start = rowp[n], len = cnt[n];
        #pragma unroll 4
        for (int j = q; j < len; j += 4) {
            int2 e = ew[start + j];
            float wv = __int_as_float(e.y);
            uint4 r = *(const uint4*)&hlin[(size_t)e.x * HH + f0];
            u32 wd[4] = {r.x, r.y, r.z, r.w};
            #pragma unroll
            for (int k = 0; k < 4; ++k) {
                a[k * 2 + 0] = fmaf(bf2f((u16)(wd[k] & 0xffff)), wv, a[k * 2 + 0]);
                a[k * 2 + 1] = fmaf(bf2f((u16)(wd[k] >> 16)),    wv, a[k * 2 + 1]);
            }
        }
        #pragma unroll
        for (int k = 0; k < 8; ++k) {
            a[k] += __shfl_xor(a[k], 16);
            a[k] += __shfl_xor(a[k], 32);
        }
        if (q == 0) {
            u32 o[4];
            #pragma unroll
            for (int k = 0; k < 4; ++k) {
                float v0 = fmaxf(a[k * 2 + 0] + bb[k * 2 + 0], 0.f);
                float v1 = fmaxf(a[k * 2 + 1] + bb[k * 2 + 1], 0.f);
                ss[k * 2 + 0] += v0; s2[k * 2 + 0] += v0 * v0;
                ss[k * 2 + 1] += v1; s2[k * 2 + 1] += v1 * v1;
                o[k] = (u32)f2b(v0) | ((u32)f2b(v1) << 16);
            }
            uint4 pk = make_uint4(o[0], o[1], o[2], o[3]);
            *(uint4*)&hout[(size_t)n * HH + f0] = pk;
        }
    }
    if (q == 0) {
        #pragma unroll
        for (int k = 0; k < 8; ++k) {
            sacc[wave][f0 + k] = ss[k];
            sacc[wave][128 + f0 + k] = s2[k];
        }
    }
    __syncthreads();
    if (t < 256) {
        float tot = sacc[0][t] + sacc[1][t] + sacc[2][t] + sacc[3][t];
        atomicAdd(&sums[t], tot);
    }
}

// ---------------- output head ----------------

__global__ __launch_bounds__(256) void k_out(const u16* __restrict__ h,
                                             const float* __restrict__ stats,
                                             const float* __restrict__ g,
                                             const float* __restrict__ be,
                                             const float* __restrict__ Wout,
                                             const float* __restrict__ bout,
                                             float* __restrict__ out) {
    __shared__ float hs[32][132];
    __shared__ float Wl[128][8];
    __shared__ float asc[128], csc[128];
    int t = threadIdx.x;
    if (t < 128) {
        float mu  = stats[256 + t] * (1.0f / NN);
        float var = stats[384 + t] * (1.0f / NN) - mu * mu;
        float rs  = rsqrtf(var + EPSV);
        float a   = g[t] * rs;
        asc[t] = a;
        csc[t] = be[t] - mu * a;
    }
    #pragma unroll
    for (int l = 0; l < 4; ++l) {
        int idx = t + l * 256;
        Wl[idx >> 3][idx & 7] = Wout[idx];
    }
    __syncthreads();

    int n0 = blockIdx.x * 32;
    #pragma unroll
    for (int l = 0; l < 2; ++l) {
        int idx = t + l * 256;
        int r = idx >> 4;
        int kg = idx & 15;
        uint4 v = *(const uint4*)&h[(size_t)(n0 + r) * HH + kg * 8];
        u32 w[4] = {v.x, v.y, v.z, v.w};
        int kk = kg * 8;
        #pragma unroll
        for (int qq = 0; qq < 4; ++qq) {
            float x0 = bf2f((u16)(w[qq] & 0xffff));
            float x1 = bf2f((u16)(w[qq] >> 16));
            hs[r][kk + qq * 2 + 0] = fmaxf(fmaf(x0, asc[kk + qq * 2 + 0], csc[kk + qq * 2 + 0]), 0.f);
            hs[r][kk + qq * 2 + 1] = fmaxf(fmaf(x1, asc[kk + qq * 2 + 1], csc[kk + qq * 2 + 1]), 0.f);
        }
    }
    __syncthreads();

    int c = t & 7, rl = t >> 3;
    float acc = 0.f;
    #pragma unroll 8
    for (int k = 0; k < 128; ++k) acc = fmaf(hs[rl][k], Wl[k][c], acc);
    out[(size_t)(n0 + rl) * CC + c] = acc + bout[c];
}

// ---------------- launch ----------------

extern "C" void kernel_launch(void* const* d_in, const int* in_sizes, int n_in,
                              void* d_out, int out_size, void* d_ws, size_t ws_size,
                              hipStream_t stream) {
    const float* x    = (const float*)d_in[0];
    const int*   src  = (const int*)d_in[1];
    const int*   dst  = (const int*)d_in[2];
    const float* sctx = (const float*)d_in[3];
    const float* W1   = (const float*)d_in[4];
    const float* b1   = (const float*)d_in[5];
    const float* g1   = (const float*)d_in[6];
    const float* be1  = (const float*)d_in[7];
    const float* W2   = (const float*)d_in[8];
    const float* b2   = (const float*)d_in[9];
    const float* g2   = (const float*)d_in[10];
    const float* be2  = (const float*)d_in[11];
    const float* Wout = (const float*)d_in[12];
    const float* bout = (const float*)d_in[13];
    float* out = (float*)d_out;

    char* p = (char*)d_ws;
    auto carve = [&](size_t bytes) -> char* {
        char* r = p;
        p += (bytes + 255) & ~(size_t)255;
        return r;
    };
    u16*   hlin    = (u16*)carve((size_t)NN * HH * 2);
    u16*   hbuf    = (u16*)carve((size_t)NN * HH * 2);
    int2*  ew      = (int2*)carve((size_t)EE * 8 + 16);
    u32*   tmp     = (u32*)carve((size_t)NB * BCAP * 4 + 16);
    int*   cnt     = (int*)carve((size_t)NN * 4);
    int*   rowp    = (int*)carve((size_t)NN * 4);
    int*   gcursor = (int*)carve((size_t)NB * 4);
    float* dinv    = (float*)carve((size_t)NN * 4);
    int*   part    = (int*)carve((size_t)NSCAN * 4);
    float* cvec    = (float*)carve(128 * 4);
    float* stats   = (float*)carve(512 * 4);
    u16*   Bt1     = (u16*)carve(128 * 64 * 2);
    u16*   Bt2     = (u16*)carve(128 * 128 * 2);

    k_zero<<<391, 256, 0, stream>>>(cnt, stats, gcursor);
    k_prep<<<97, 256, 0, stream>>>(sctx, W1, W2, cvec, Bt1, Bt2);
    k_bin<<<NBLK_BIN, 256, 0, stream>>>(src, dst, cnt, gcursor, tmp);
    k_part<<<NSCAN, 256, 0, stream>>>(cnt, part, dinv);
    k_scanpart<<<1, 256, 0, stream>>>(part);
    k_scanchunk<<<NSCAN, 512, 0, stream>>>(cnt, part, rowp);
    k_csr<<<NB, 256, 0, stream>>>(tmp, gcursor, rowp, dinv, ew);

    k_mgemm1<<<(NN + 63) / 64, 256, 0, stream>>>(x, Bt1, cvec, hlin);
    k_spmm<<<2048, 256, 0, stream>>>(hlin, rowp, cnt, ew, dinv, b1, hbuf, stats);
    k_mgemm2<<<(NN + 63) / 64, 256, 0, stream>>>(hbuf, Bt2, stats, g1, be1, hlin);
    k_spmm<<<2048, 256, 0, stream>>>(hlin, rowp, cnt, ew, dinv, b2, hbuf, stats + 256);
    k_out<<<NN / 32, 256, 0, stream>>>(hbuf, stats, g2, be2, Wout, bout, out);
}

// Round 6
// 334.229 us; speedup vs baseline: 2.1466x; 1.1304x over previous
//
#include <hip/hip_runtime.h>
#include <math.h>

#define NN 100000
#define EE 1600000
#define HH 128
#define DX 64
#define CC 8
#define EPSV 1e-5f

#define CHUNK 512
#define NSCAN ((NN + CHUNK - 1) / CHUNK)   // 196

#define NB 782          // ceil(NN/128) coarse buckets of 128 nodes
#define BCAP 4096       // fixed tmp capacity per bucket
#define EPB 4096        // edges per k_bin block
#define NBLK_BIN ((EE + EPB - 1) / EPB)    // 391

#define SPMM_GRID 12500 // 6x resident capacity -> dynamic load balance
#define SBANK 16        // banked stats accumulators

typedef unsigned int u32;
typedef unsigned short u16;
typedef __attribute__((ext_vector_type(8))) short short8v;
typedef __attribute__((ext_vector_type(4))) float float4v;

__device__ __forceinline__ float bf2f(u16 h) {
    u32 u = ((u32)h) << 16;
    union { u32 u; float f; } c; c.u = u; return c.f;
}
__device__ __forceinline__ u16 f2b(float f) {
    union { float f; u32 u; } c; c.f = f;
    u32 r = (c.u + 0x7fffu + ((c.u >> 16) & 1u)) >> 16;
    return (u16)r;
}

// ---------------- setup ----------------

__global__ void k_zero(int* __restrict__ cnt, float* __restrict__ stats,
                       int* __restrict__ gcursor) {
    int i = blockIdx.x * blockDim.x + threadIdx.x;
    if (i < NN) cnt[i] = 0;
    if (i < 2 * SBANK * 256) stats[i] = 0.f;
    if (i < NB) gcursor[i] = i * BCAP;
}

__global__ void k_prep(const float* __restrict__ sctx,
                       const float* __restrict__ W1, const float* __restrict__ W2,
                       float* __restrict__ cvec,
                       u16* __restrict__ Bt1, u16* __restrict__ Bt2) {
    int i = blockIdx.x * 256 + threadIdx.x;
    if (i < 128 * 64) {
        int col = i >> 6, k = i & 63;
        Bt1[i] = f2b(W1[(size_t)k * HH + col]);
    } else if (i < 128 * 64 + 128 * 128) {
        int j = i - 128 * 64;
        int col = j >> 7, k = j & 127;
        Bt2[j] = f2b(W2[(size_t)k * HH + col]);
    }
    if (blockIdx.x == 96 && threadIdx.x < 128) {
        int f = threadIdx.x;
        float s = 0.f;
        #pragma unroll
        for (int j = 0; j < 64; ++j) s += sctx[j] * W1[(64 + j) * HH + f];
        cvec[f] = s;
    }
}

// bin edges into fixed per-bucket regions; fused degree count
__global__ __launch_bounds__(256) void k_bin(const int* __restrict__ src,
                                             const int* __restrict__ dst,
                                             int* __restrict__ cnt,
                                             int* __restrict__ gcursor,
                                             u32* __restrict__ tmp) {
    __shared__ int bcnt[NB], gbase[NB], bofs[NB];
    int t = threadIdx.x;
    int e0 = blockIdx.x * EPB;
    for (int i = t; i < NB; i += 256) { bcnt[i] = 0; bofs[i] = 0; }
    __syncthreads();
    int myd[16], mys[16];
    #pragma unroll
    for (int i = 0; i < 16; ++i) {
        int e = e0 + t + i * 256;
        int d = -1, s = 0;
        if (e < EE) {
            d = dst[e]; s = src[e];
            atomicAdd(&bcnt[d >> 7], 1);
            atomicAdd(&cnt[d], 1);
        }
        myd[i] = d; mys[i] = s;
    }
    __syncthreads();
    for (int b = t; b < NB; b += 256) {
        int c = bcnt[b];
        if (c) gbase[b] = atomicAdd(&gcursor[b], c);
    }
    __syncthreads();
    #pragma unroll
    for (int i = 0; i < 16; ++i) {
        int d = myd[i];
        if (d >= 0) {
            int b = d >> 7;
            int lp = atomicAdd(&bofs[b], 1);
            tmp[gbase[b] + lp] = (u32)mys[i] | ((u32)(d & 127) << 17);
        }
    }
}

__global__ void k_part(const int* __restrict__ cnt, int* __restrict__ part,
                       float* __restrict__ dinv) {
    __shared__ int ls[256];
    int b = blockIdx.x, t = threadIdx.x;
    int base = b * CHUNK;
    int s = 0;
    for (int i = t; i < CHUNK; i += 256) {
        int idx = base + i;
        if (idx < NN) {
            int c = cnt[idx];
            s += c;
            dinv[idx] = rsqrtf(1.0f + (float)c);
        }
    }
    ls[t] = s; __syncthreads();
    for (int d = 128; d > 0; d >>= 1) {
        if (t < d) ls[t] += ls[t + d];
        __syncthreads();
    }
    if (t == 0) part[b] = ls[0];
}

__global__ void k_scanpart(int* __restrict__ part) {
    __shared__ int ls[256];
    int t = threadIdx.x;
    int v = (t < NSCAN) ? part[t] : 0;
    ls[t] = v; __syncthreads();
    for (int d = 1; d < 256; d <<= 1) {
        int x = (t >= d) ? ls[t - d] : 0;
        __syncthreads();
        ls[t] += x;
        __syncthreads();
    }
    if (t < NSCAN) part[t] = ls[t] - v;   // exclusive
}

__global__ void k_scanchunk(const int* __restrict__ cnt, const int* __restrict__ part,
                            int* __restrict__ row_ptr) {
    __shared__ int ls[CHUNK];
    int b = blockIdx.x, t = threadIdx.x;
    int idx = b * CHUNK + t;
    int v = (idx < NN) ? cnt[idx] : 0;
    ls[t] = v; __syncthreads();
    for (int d = 1; d < CHUNK; d <<= 1) {
        int x = (t >= d) ? ls[t - d] : 0;
        __syncthreads();
        ls[t] += x;
        __syncthreads();
    }
    if (idx < NN) row_ptr[idx] = part[b] + ls[t] - v;
}

__global__ __launch_bounds__(256) void k_csr(const u32* __restrict__ tmp,
                                             const int* __restrict__ gcursor,
                                             const int* __restrict__ rowp,
                                             const float* __restrict__ dinv,
                                             int2* __restrict__ ew) {
    __shared__ int lcur[128];
    __shared__ float ldin[128];
    int b = blockIdx.x, t = threadIdx.x;
    int n0 = b << 7;
    if (t < 128) {
        int n = n0 + t;
        lcur[t] = (n < NN) ? rowp[n] : 0;
        ldin[t] = (n < NN) ? dinv[n] : 0.f;
    }
    __syncthreads();
    int beg = b * BCAP;
    int end = gcursor[b];
    for (int i = beg + t; i < end; i += 256) {
        u32 r = tmp[i];
        int s = r & 0x1FFFF;
        int dl = (r >> 17) & 127;
        int pos = atomicAdd(&lcur[dl], 1);
        float w = dinv[s] * ldin[dl];
        ew[pos] = make_int2(s, __float_as_int(w));
    }
}

// ---------------- MFMA GEMM1 ----------------

__global__ __launch_bounds__(256) void k_mgemm1(const float* __restrict__ x,
                                                const u16* __restrict__ Bt1,
                                                const float* __restrict__ cvec,
                                                u16* __restrict__ outp) {
    __shared__ u16 As[64 * 64];
    __shared__ u16 Bs[128 * 64];
    __shared__ float cvs[128];
    int t = threadIdx.x;
    int n0 = blockIdx.x * 64;
    if (t < 128) cvs[t] = cvec[t];

    #pragma unroll
    for (int l = 0; l < 4; ++l) {
        int idx = t + l * 256;
        int col = idx >> 3, kg = idx & 7;
        uint4 v = *(const uint4*)&Bt1[idx * 8];
        u32 byte = (u32)(col * 128 + kg * 16) ^ ((col & 7) << 4);
        *(uint4*)((char*)Bs + byte) = v;
    }
    #pragma unroll
    for (int l = 0; l < 4; ++l) {
        int idx = t + l * 256;
        int r = idx >> 4, fg = idx & 15;
        int n = n0 + r; if (n > NN - 1) n = NN - 1;
        float4 v = *(const float4*)&x[(size_t)n * DX + fg * 4];
        u32 lo = (u32)f2b(v.x) | ((u32)f2b(v.y) << 16);
        u32 hi = (u32)f2b(v.z) | ((u32)f2b(v.w) << 16);
        u32 byte = (u32)(r * 128 + fg * 8) ^ ((r & 7) << 4);
        *(uint2*)((char*)As + byte) = make_uint2(lo, hi);
    }
    __syncthreads();

    int w = t >> 6, lane = t & 63;
    int rl = lane & 15, kq = lane >> 4;
    int rbase = w * 16 + rl;
    float4v acc[8];
    #pragma unroll
    for (int nt = 0; nt < 8; ++nt) acc[nt] = (float4v){0.f, 0.f, 0.f, 0.f};

    #pragma unroll
    for (int kk = 0; kk < 2; ++kk) {
        u32 ab = (u32)(rbase * 128 + kk * 64 + kq * 16) ^ ((rbase & 7) << 4);
        short8v af = *(const short8v*)((const char*)As + ab);
        #pragma unroll
        for (int nt = 0; nt < 8; ++nt) {
            int col = nt * 16 + rl;
            u32 bb = (u32)(col * 128 + kk * 64 + kq * 16) ^ ((col & 7) << 4);
            short8v bf = *(const short8v*)((const char*)Bs + bb);
            acc[nt] = __builtin_amdgcn_mfma_f32_16x16x32_bf16(af, bf, acc[nt], 0, 0, 0);
        }
    }
    __syncthreads();
    #pragma unroll
    for (int nt = 0; nt < 8; ++nt) {
        int col = nt * 16 + rl;
        #pragma unroll
        for (int j = 0; j < 4; ++j) {
            int row = w * 16 + kq * 4 + j;
            u16 v = f2b(acc[nt][j] + cvs[col]);
            u32 byte = (u32)(row * 256 + col * 2) ^ ((row & 7) << 4);
            *(u16*)((char*)Bs + byte) = v;
        }
    }
    __syncthreads();
    #pragma unroll
    for (int l = 0; l < 4; ++l) {
        int idx = t + l * 256;
        int r = idx >> 4, kg = idx & 15;
        u32 byte = (u32)(r * 256 + kg * 16) ^ ((r & 7) << 4);
        uint4 v = *(const uint4*)((const char*)Bs + byte);
        int n = n0 + r;
        if (n < NN) *(uint4*)&outp[(size_t)n * HH + kg * 8] = v;
    }
}

// ---------------- MFMA GEMM2 (banked stats in) ----------------

__global__ __launch_bounds__(256) void k_mgemm2(const u16* __restrict__ hin,
                                                const u16* __restrict__ Bt2,
                                                const float* __restrict__ stats,
                                                const float* __restrict__ g,
                                                const float* __restrict__ be,
                                                u16* __restrict__ outp) {
    __shared__ u16 As[64 * 128];
    __shared__ u16 Bs[128 * 128];
    __shared__ float asc[128], csc[128];
    int t = threadIdx.x;
    int n0 = blockIdx.x * 64;
    if (t < 128) {
        float s = 0.f, s2 = 0.f;
        #pragma unroll
        for (int bk = 0; bk < SBANK; ++bk) {
            s  += stats[bk * 256 + t];
            s2 += stats[bk * 256 + 128 + t];
        }
        float mu  = s * (1.0f / NN);
        float var = s2 * (1.0f / NN) - mu * mu;
        float rs  = rsqrtf(var + EPSV);
        float a   = g[t] * rs;
        asc[t] = a;
        csc[t] = be[t] - mu * a;
    }
    #pragma unroll
    for (int l = 0; l < 8; ++l) {
        int idx = t + l * 256;
        int col = idx >> 4, kg = idx & 15;
        uint4 v = *(const uint4*)&Bt2[idx * 8];
        u32 byte = (u32)(col * 256 + kg * 16) ^ ((col & 7) << 4);
        *(uint4*)((char*)Bs + byte) = v;
    }
    __syncthreads();
    #pragma unroll
    for (int l = 0; l < 4; ++l) {
        int idx = t + l * 256;
        int r = idx >> 4, kg = idx & 15;
        int n = n0 + r; if (n > NN - 1) n = NN - 1;
        uint4 v = *(const uint4*)&hin[(size_t)n * HH + kg * 8];
        u32 wds[4] = {v.x, v.y, v.z, v.w};
        u32 pk[2][2];
        #pragma unroll
        for (int q = 0; q < 4; ++q) {
            int k = kg * 8 + q * 2;
            float x0 = bf2f((u16)(wds[q] & 0xffff));
            float x1 = bf2f((u16)(wds[q] >> 16));
            u16 o0 = f2b(fmaxf(fmaf(x0, asc[k],     csc[k]),     0.f));
            u16 o1 = f2b(fmaxf(fmaf(x1, asc[k + 1], csc[k + 1]), 0.f));
            pk[q >> 1][q & 1] = (u32)o0 | ((u32)o1 << 16);
        }
        uint4 ov = make_uint4(pk[0][0], pk[0][1], pk[1][0], pk[1][1]);
        u32 byte = (u32)(r * 256 + kg * 16) ^ ((r & 7) << 4);
        *(uint4*)((char*)As + byte) = ov;
    }
    __syncthreads();

    int w = t >> 6, lane = t & 63;
    int rl = lane & 15, kq = lane >> 4;
    int rbase = w * 16 + rl;
    float4v acc[8];
    #pragma unroll
    for (int nt = 0; nt < 8; ++nt) acc[nt] = (float4v){0.f, 0.f, 0.f, 0.f};

    #pragma unroll
    for (int kk = 0; kk < 4; ++kk) {
        u32 ab = (u32)(rbase * 256 + kk * 64 + kq * 16) ^ ((rbase & 7) << 4);
        short8v af = *(const short8v*)((const char*)As + ab);
        #pragma unroll
        for (int nt = 0; nt < 8; ++nt) {
            int col = nt * 16 + rl;
            u32 bb = (u32)(col * 256 + kk * 64 + kq * 16) ^ ((col & 7) << 4);
            short8v bf = *(const short8v*)((const char*)Bs + bb);
            acc[nt] = __builtin_amdgcn_mfma_f32_16x16x32_bf16(af, bf, acc[nt], 0, 0, 0);
        }
    }
    __syncthreads();
    #pragma unroll
    for (int nt = 0; nt < 8; ++nt) {
        int col = nt * 16 + rl;
        #pragma unroll
        for (int j = 0; j < 4; ++j) {
            int row = w * 16 + kq * 4 + j;
            u16 v = f2b(acc[nt][j]);
            u32 byte = (u32)(row * 256 + col * 2) ^ ((row & 7) << 4);
            *(u16*)((char*)As + byte) = v;
        }
    }
    __syncthreads();
    #pragma unroll
    for (int l = 0; l < 4; ++l) {
        int idx = t + l * 256;
        int r = idx >> 4, kg = idx & 15;
        u32 byte = (u32)(r * 256 + kg * 16) ^ ((r & 7) << 4);
        uint4 v = *(const uint4*)((const char*)As + byte);
        int n = n0 + r;
        if (n < NN) *(uint4*)&outp[(size_t)n * HH + kg * 8] = v;
    }
}

// ---------------- SpMM + fused BN stats (banked flush) ----------------

__global__ __launch_bounds__(256) void k_spmm(const u16* __restrict__ hlin,
                                              const int* __restrict__ rowp,
                                              const int* __restrict__ cnt,
                                              const int2* __restrict__ ew,
                                              const float* __restrict__ dinv,
                                              const float* __restrict__ b,
                                              u16* __restrict__ hout,
                                              float* __restrict__ sums) {
    __shared__ float sacc[4][256];
    int t = threadIdx.x;
    int wave = t >> 6, lane = t & 63;
    int q = lane >> 4, li = lane & 15;
    int f0 = li * 8;
    float bb[8];
    {
        float4 b0 = *(const float4*)&b[f0];
        float4 b1 = *(const float4*)&b[f0 + 4];
        bb[0] = b0.x; bb[1] = b0.y; bb[2] = b0.z; bb[3] = b0.w;
        bb[4] = b1.x; bb[5] = b1.y; bb[6] = b1.z; bb[7] = b1.w;
    }
    float ss[8], s2[8];
    #pragma unroll
    for (int k = 0; k < 8; ++k) { ss[k] = 0.f; s2[k] = 0.f; }

    for (int n = blockIdx.x * 4 + wave; n < NN; n += gridDim.x * 4) {
        float dn = dinv[n];
        float a[8];
        {
            uint4 r = *(const uint4*)&hlin[(size_t)n * HH + f0];
            float sc = (q == 0) ? dn * dn : 0.f;
            u32 wd[4] = {r.x, r.y, r.z, r.w};
            #pragma unroll
            for (int j = 0; j < 4; ++j) {
                a[j * 2 + 0] = sc * bf2f((u16)(wd[j] & 0xffff));
                a[j * 2 + 1] = sc * bf2f((u16)(wd[j] >> 16));
            }
        }
        int start = rowp[n], len = cnt[n];
        #pragma unroll 4
        for (int j = q; j < len; j += 4) {
            int2 e = ew[start + j];
            float wv = __int_as_float(e.y);
            uint4 r = *(const uint4*)&hlin[(size_t)e.x * HH + f0];
            u32 wd[4] = {r.x, r.y, r.z, r.w};
            #pragma unroll
            for (int k = 0; k < 4; ++k) {
                a[k * 2 + 0] = fmaf(bf2f((u16)(wd[k] & 0xffff)), wv, a[k * 2 + 0]);
                a[k * 2 + 1] = fmaf(bf2f((u16)(wd[k] >> 16)),    wv, a[k * 2 + 1]);
            }
        }
        #pragma unroll
        for (int k = 0; k < 8; ++k) {
            a[k] += __shfl_xor(a[k], 16);
            a[k] += __shfl_xor(a[k], 32);
        }
        if (q == 0) {
            u32 o[4];
            #pragma unroll
            for (int k = 0; k < 4; ++k) {
                float v0 = fmaxf(a[k * 2 + 0] + bb[k * 2 + 0], 0.f);
                float v1 = fmaxf(a[k * 2 + 1] + bb[k * 2 + 1], 0.f);
                ss[k * 2 + 0] += v0; s2[k * 2 + 0] += v0 * v0;
                ss[k * 2 + 1] += v1; s2[k * 2 + 1] += v1 * v1;
                o[k] = (u32)f2b(v0) | ((u32)f2b(v1) << 16);
            }
            uint4 pk = make_uint4(o[0], o[1], o[2], o[3]);
            *(uint4*)&hout[(size_t)n * HH + f0] = pk;
        }
    }
    // flush: k-major layout -> 16 lanes hit 16 distinct banks per store
    if (q == 0) {
        #pragma unroll
        for (int k = 0; k < 8; ++k) {
            sacc[wave][k * 16 + li] = ss[k];
            sacc[wave][128 + k * 16 + li] = s2[k];
        }
    }
    __syncthreads();
    {
        int f = t & 127;
        int pos = (t & 128) + (f & 7) * 16 + (f >> 3);
        float tot = sacc[0][pos] + sacc[1][pos] + sacc[2][pos] + sacc[3][pos];
        atomicAdd(&sums[(blockIdx.x & (SBANK - 1)) * 256 + t], tot);
    }
}

// ---------------- output head (banked stats in) ----------------

__global__ __launch_bounds__(256) void k_out(const u16* __restrict__ h,
                                             const float* __restrict__ stats2,
                                             const float* __restrict__ g,
                                             const float* __restrict__ be,
                                             const float* __restrict__ Wout,
                                             const float* __restrict__ bout,
                                             float* __restrict__ out) {
    __shared__ float hs[32][132];
    __shared__ float Wl[128][8];
    __shared__ float asc[128], csc[128];
    int t = threadIdx.x;
    if (t < 128) {
        float s = 0.f, s2 = 0.f;
        #pragma unroll
        for (int bk = 0; bk < SBANK; ++bk) {
            s  += stats2[bk * 256 + t];
            s2 += stats2[bk * 256 + 128 + t];
        }
        float mu  = s * (1.0f / NN);
        float var = s2 * (1.0f / NN) - mu * mu;
        float rs  = rsqrtf(var + EPSV);
        float a   = g[t] * rs;
        asc[t] = a;
        csc[t] = be[t] - mu * a;
    }
    #pragma unroll
    for (int l = 0; l < 4; ++l) {
        int idx = t + l * 256;
        Wl[idx >> 3][idx & 7] = Wout[idx];
    }
    __syncthreads();

    int n0 = blockIdx.x * 32;
    #pragma unroll
    for (int l = 0; l < 2; ++l) {
        int idx = t + l * 256;
        int r = idx >> 4;
        int kg = idx & 15;
        uint4 v = *(const uint4*)&h[(size_t)(n0 + r) * HH + kg * 8];
        u32 w[4] = {v.x, v.y, v.z, v.w};
        int kk = kg * 8;
        #pragma unroll
        for (int qq = 0; qq < 4; ++qq) {
            float x0 = bf2f((u16)(w[qq] & 0xffff));
            float x1 = bf2f((u16)(w[qq] >> 16));
            hs[r][kk + qq * 2 + 0] = fmaxf(fmaf(x0, asc[kk + qq * 2 + 0], csc[kk + qq * 2 + 0]), 0.f);
            hs[r][kk + qq * 2 + 1] = fmaxf(fmaf(x1, asc[kk + qq * 2 + 1], csc[kk + qq * 2 + 1]), 0.f);
        }
    }
    __syncthreads();

    int c = t & 7, rl = t >> 3;
    float acc = 0.f;
    #pragma unroll 8
    for (int k = 0; k < 128; ++k) acc = fmaf(hs[rl][k], Wl[k][c], acc);
    out[(size_t)(n0 + rl) * CC + c] = acc + bout[c];
}

// ---------------- launch ----------------

extern "C" void kernel_launch(void* const* d_in, const int* in_sizes, int n_in,
                              void* d_out, int out_size, void* d_ws, size_t ws_size,
                              hipStream_t stream) {
    const float* x    = (const float*)d_in[0];
    const int*   src  = (const int*)d_in[1];
    const int*   dst  = (const int*)d_in[2];
    const float* sctx = (const float*)d_in[3];
    const float* W1   = (const float*)d_in[4];
    const float* b1   = (const float*)d_in[5];
    const float* g1   = (const float*)d_in[6];
    const float* be1  = (const float*)d_in[7];
    const float* W2   = (const float*)d_in[8];
    const float* b2   = (const float*)d_in[9];
    const float* g2   = (const float*)d_in[10];
    const float* be2  = (const float*)d_in[11];
    const float* Wout = (const float*)d_in[12];
    const float* bout = (const float*)d_in[13];
    float* out = (float*)d_out;

    char* p = (char*)d_ws;
    auto carve = [&](size_t bytes) -> char* {
        char* r = p;
        p += (bytes + 255) & ~(size_t)255;
        return r;
    };
    u16*   hlin    = (u16*)carve((size_t)NN * HH * 2);
    u16*   hbuf    = (u16*)carve((size_t)NN * HH * 2);
    int2*  ew      = (int2*)carve((size_t)EE * 8 + 16);
    u32*   tmp     = (u32*)carve((size_t)NB * BCAP * 4 + 16);
    int*   cnt     = (int*)carve((size_t)NN * 4);
    int*   rowp    = (int*)carve((size_t)NN * 4);
    int*   gcursor = (int*)carve((size_t)NB * 4);
    float* dinv    = (float*)carve((size_t)NN * 4);
    int*   part    = (int*)carve((size_t)NSCAN * 4);
    float* cvec    = (float*)carve(128 * 4);
    float* stats   = (float*)carve((size_t)2 * SBANK * 256 * 4);
    u16*   Bt1     = (u16*)carve(128 * 64 * 2);
    u16*   Bt2     = (u16*)carve(128 * 128 * 2);

    k_zero<<<391, 256, 0, stream>>>(cnt, stats, gcursor);
    k_prep<<<97, 256, 0, stream>>>(sctx, W1, W2, cvec, Bt1, Bt2);
    k_bin<<<NBLK_BIN, 256, 0, stream>>>(src, dst, cnt, gcursor, tmp);
    k_part<<<NSCAN, 256, 0, stream>>>(cnt, part, dinv);
    k_scanpart<<<1, 256, 0, stream>>>(part);
    k_scanchunk<<<NSCAN, 512, 0, stream>>>(cnt, part, rowp);
    k_csr<<<NB, 256, 0, stream>>>(tmp, gcursor, rowp, dinv, ew);

    k_mgemm1<<<(NN + 63) / 64, 256, 0, stream>>>(x, Bt1, cvec, hlin);
    k_spmm<<<SPMM_GRID, 256, 0, stream>>>(hlin, rowp, cnt, ew, dinv, b1, hbuf, stats);
    k_mgemm2<<<(NN + 63) / 64, 256, 0, stream>>>(hbuf, Bt2, stats, g1, be1, hlin);
    k_spmm<<<SPMM_GRID, 256, 0, stream>>>(hlin, rowp, cnt, ew, dinv, b2, hbuf, stats + SBANK * 256);
    k_out<<<NN / 32, 256, 0, stream>>>(hbuf, stats + SBANK * 256, g2, be2, Wout, bout, out);
}